// Round 14
// baseline (286.876 us; speedup 1.0000x reference)
//
#include <hip/hip_runtime.h>
#include <hip/hip_bf16.h>
#include <math.h>

typedef __bf16 bf16;
typedef __attribute__((ext_vector_type(4))) __bf16 bf16x4;
typedef __attribute__((ext_vector_type(8))) __bf16 bf16x8;
typedef __attribute__((ext_vector_type(4))) float f32x4;

// ---------------- problem constants ----------------
constexpr int NN   = 10000;
constexpr int NPAD = 10112;            // 128-aligned (DMA overrun pad)
constexpr int BN = 176, BK = 64;

// ---------------- workspace layout (bytes) ----------------
constexpr size_t FCWT_OFF = 0;                         // bf16 [528][576]   fcw^T (zero-padded)
constexpr size_t M1WT_OFF = 608256;                    // bf16 [176][704]
constexpr size_t M2WT_OFF = 856064;                    // bf16 [176][192]
constexpr size_t WKH_OFF  = 923648;                    // bf16 [2*576][320] wk head-slices
constexpr size_t WQHT_OFF = 1660928;                   // bf16 [2*352][320] wq head-slices (rows<172)
constexpr size_t WVH_OFF  = 2111488;                   // bf16 [2*704][320] wv head-slices
constexpr size_t WQKT_OFF = 3012608;                   // bf16 [1232][192]  WQK^T (qk GEMM B)
constexpr size_t WVFT_OFF = 3485696;                   // bf16 [528][1152]  WVF^T (fusedFC B)
constexpr size_t QB_OFF   = 4702208;                   // f32 [516]
constexpr size_t QKB_OFF  = 4706304;                   // f32 [1232]
constexpr size_t CPH_OFF  = 4714496;                   // f32 [172]
constexpr size_t NH16_OFF = 4715520;                   // bf16 [NPAD][192]
constexpr size_t QK_OFF   = NH16_OFF + (size_t)NPAD*192*2;    // bf16 [NPAD][1152]
constexpr size_t ZB_OFF   = QK_OFF   + (size_t)NPAD*1152*2;   // bf16 [NPAD][1152]
constexpr size_t FCR_OFF  = ZB_OFF   + (size_t)NPAD*1152*2;   // f32 [NN][516]
constexpr size_t X_OFF    = FCR_OFF  + (size_t)NN*516*4;      // bf16 [NPAD][704]
constexpr size_t R_OFF    = X_OFF    + (size_t)NPAD*704*2;    // bf16 [NPAD][192]

// ---------------- global_load_lds helper (width 16) ----------------
typedef __attribute__((address_space(3))) void lds_void;
typedef const __attribute__((address_space(1))) void glb_void;
__device__ __forceinline__ void gload16(const void* g, void* l) {
    __builtin_amdgcn_global_load_lds((glb_void*)(uintptr_t)g,
                                     (lds_void*)(unsigned int)(uintptr_t)l, 16, 0, 0);
}

// ---------------- tiled transpose-pack (fcw, m1w, m2w) ----------------
__global__ __launch_bounds__(256)
void packT_kernel(const float* __restrict__ fcw, const float* __restrict__ m1w,
                  const float* __restrict__ m2w,
                  bf16* __restrict__ FCWT, bf16* __restrict__ M1WT, bf16* __restrict__ M2WT) {
    __shared__ float tile[32][33];
    const float* src; bf16* dst; int K, C, LD;
    switch (blockIdx.y) {
        case 0:  src = fcw; K = 516; C = 516; dst = FCWT; LD = 576; break;
        case 1:  src = m1w; K = 688; C = 172; dst = M1WT; LD = 704; break;
        default: src = m2w; K = 172; C = 172; dst = M2WT; LD = 192; break;
    }
    const int tilesC = (C + 31) >> 5, tilesK = (K + 31) >> 5;
    const int nt = tilesC * tilesK;
    const int tx = threadIdx.x & 31, ty = threadIdx.x >> 5;
    for (int tb = blockIdx.x; tb < nt; tb += gridDim.x) {
        int tc = tb % tilesC, tk = tb / tilesC;
        #pragma unroll
        for (int i = 0; i < 4; ++i) {
            int k = tk*32 + ty + i*8, c = tc*32 + tx;
            tile[ty + i*8][tx] = (k < K && c < C) ? src[(size_t)k*C + c] : 0.f;
        }
        __syncthreads();
        #pragma unroll
        for (int i = 0; i < 4; ++i) {
            int c = tc*32 + ty + i*8, k = tk*32 + tx;
            if (c < C && k < K) dst[(size_t)c*LD + k] = (bf16)tile[tx][ty + i*8];
        }
        __syncthreads();
    }
}

// ---------------- fused misc packs: slices + nh16 + cph + qbias ----------------
__global__ void pack_misc_kernel(const float* __restrict__ wk, const float* __restrict__ wq,
                                 const float* __restrict__ wv, const float* __restrict__ node_h,
                                 const float* __restrict__ phase,
                                 bf16* __restrict__ WKH, bf16* __restrict__ WQHT,
                                 bf16* __restrict__ WVH, bf16* __restrict__ nh16,
                                 float* __restrict__ cph, float* __restrict__ QB) {
    constexpr int T0 = 2*516*258;
    constexpr int T1 = T0 + 2*172*258;
    constexpr int T2 = T1 + 2*516*258;
    constexpr int T3 = T2 + NN*192;
    constexpr int T4 = T3 + 172;
    constexpr int T5 = T4 + 516;
    for (int idx = blockIdx.x * blockDim.x + threadIdx.x; idx < T5;
         idx += gridDim.x * blockDim.x) {
        if (idx < T0) {
            int h = idx / (516*258), rem = idx % (516*258), d = rem / 258, j = rem % 258;
            WKH[((size_t)h*576 + d)*320 + j] = (bf16)wk[(size_t)d*516 + h*258 + j];
        } else if (idx < T1) {
            int i = idx - T0;
            int h = i / (172*258), rem = i % (172*258), k = rem / 258, j = rem % 258;
            WQHT[((size_t)h*352 + k)*320 + j] = (bf16)wq[(size_t)k*516 + h*258 + j];
        } else if (idx < T2) {
            int i = idx - T1;
            int h = i / (516*258), rem = i % (516*258), c = rem / 258, j = rem % 258;
            WVH[((size_t)h*704 + c)*320 + j] = (bf16)wv[(size_t)c*516 + h*258 + j];
        } else if (idx < T3) {
            int i = idx - T2, r = i / 192, c = i % 192;
            nh16[i] = (c < 172) ? (bf16)node_h[(size_t)r*172 + c] : (bf16)0.f;
        } else if (idx < T4) {
            cph[idx - T3] = cosf(phase[idx - T3]);
        } else {
            int c = idx - T4;
            float s = 0.f;
            for (int j = 0; j < 172; ++j)
                s += cosf(phase[j]) * wq[(size_t)(344 + j) * 516 + c];
            QB[c] = s;
        }
    }
}

// qkb[h*576+d] = sum_{j<258} QB[h*258+j] * wk[d][h*258+j]   (d<516, else 0)
__global__ __launch_bounds__(256)
void qkb_kernel(const float* __restrict__ wk, const float* __restrict__ QB,
                float* __restrict__ qkb) {
    __shared__ float red[256];
    const int hd = blockIdx.x, h = hd / 576, d = hd % 576, t = threadIdx.x;
    float a = 0.f;
    if (d < 516) {
        a = QB[h*258 + t] * wk[(size_t)d*516 + h*258 + t];
        if (t < 2) a += QB[h*258 + 256 + t] * wk[(size_t)d*516 + h*258 + 256 + t];
    }
    red[t] = a; __syncthreads();
    #pragma unroll
    for (int o = 128; o; o >>= 1) { if (t < o) red[t] += red[t + o]; __syncthreads(); }
    if (t == 0) qkb[hd] = red[0];
}

// ---------------- MFMA GEMM (DMA staging + 2-phase dbuf), MT row-tiles/wave ----------------
// EPI 0: bf16 out +bias   EPI 2: f32 out +bias +selfz   EPI 3: bf16 relu(+bias), 0 past Nreal
// EPI 4: f32 out +bias
template<int KP, int EPI, int MT>
__global__ __launch_bounds__(256, 2)
void gemm_kernel(const bf16* __restrict__ A, int lda, const bf16* __restrict__ Bt,
                 float* __restrict__ outF, bf16* __restrict__ outB, int ldo,
                 const float* __restrict__ bias,
                 const float* __restrict__ aux0, const float* __restrict__ aux1,
                 int Mreal, int Nreal) {
    constexpr int NT  = KP / BK;
    constexpr int BMt = 64 * MT;
    __shared__ __align__(16) bf16 As[2][BMt][BK];
    __shared__ __align__(16) bf16 Bs[2][BN][BK];

    const int tid  = threadIdx.x;
    const int w    = tid >> 6;
    const int lane = tid & 63;
    const int lr   = lane & 15;
    const int ls   = lane >> 4;
    const int lrow = lane >> 3;
    const int lcol = (lane & 7) * 8;

    const bf16* aBase = A  + (size_t)(blockIdx.y * BMt + w * 16 * MT + lrow) * lda + lcol;
    const bf16* bBase = Bt + (size_t)(blockIdx.x * BN + lrow) * KP + lcol;

    auto stage = [&](int buf, int k0) {
        #pragma unroll
        for (int i = 0; i < 2 * MT; ++i)
            gload16(aBase + (size_t)(i * 8) * lda + k0, &As[buf][w * 16 * MT + i * 8][0]);
        #pragma unroll
        for (int jj = 0; jj < 6; ++jj) {
            int j = jj * 4 + w;
            if (j < 22) gload16(bBase + (size_t)(j * 8) * KP + k0, &Bs[buf][j * 8][0]);
        }
    };

    f32x4 acc[MT][11];
    #pragma unroll
    for (int a = 0; a < MT; ++a)
        #pragma unroll
        for (int b2 = 0; b2 < 11; ++b2) acc[a][b2] = (f32x4)(0.0f);

    stage(0, 0);
    __syncthreads();
    int cur = 0;
    for (int t = 0; t < NT; ++t) {
        if (t + 1 < NT) stage(cur ^ 1, (t + 1) * BK);
        #pragma unroll
        for (int kk = 0; kk < 2; ++kk) {
            bf16x8 afr[MT];
            #pragma unroll
            for (int mt = 0; mt < MT; ++mt)
                afr[mt] = *(const bf16x8*)&As[cur][w*16*MT + mt*16 + lr][kk*32 + ls*8];
            #pragma unroll
            for (int nt = 0; nt < 11; ++nt) {
                bf16x8 bfr = *(const bf16x8*)&Bs[cur][nt*16 + lr][kk*32 + ls*8];
                #pragma unroll
                for (int mt = 0; mt < MT; ++mt)
                    acc[mt][nt] = __builtin_amdgcn_mfma_f32_16x16x32_bf16(afr[mt], bfr, acc[mt][nt], 0, 0, 0);
            }
        }
        __syncthreads();
        cur ^= 1;
    }

    const int colb = blockIdx.x * BN + lr;
    const int rowb = blockIdx.y * BMt + w*16*MT + ls*4;
    #pragma unroll
    for (int mt = 0; mt < MT; ++mt)
    #pragma unroll
    for (int nt = 0; nt < 11; ++nt)
    #pragma unroll
    for (int q2 = 0; q2 < 4; ++q2) {
        int row = rowb + mt*16 + q2;
        int col = colb + nt*16;
        if (row >= Mreal) continue;
        float v = acc[mt][nt][q2];
        if constexpr (EPI == 0) {
            if (col < Nreal) outB[(size_t)row*ldo + col] = (bf16)(v + bias[col]);
        } else if constexpr (EPI == 2) {
            if (col < Nreal) {
                float sz = (col < 172) ? aux0[(size_t)row*172 + col]
                                       : ((col < 344) ? 0.f : aux1[col - 344]);
                outF[(size_t)row*ldo + col] = v + bias[col] + sz;
            }
        } else if constexpr (EPI == 3) {
            float vv = (col < Nreal) ? fmaxf(v + bias[col], 0.f) : 0.f;
            outB[(size_t)row*ldo + col] = (bf16)vv;
        } else {
            if (col < Nreal) outF[(size_t)row*ldo + col] = v + bias[col];
        }
    }
}

// ---------------- combined WQK/WVF GEMMs (KP=320, bf16 plain out), blockIdx.z selects ----------------
__global__ __launch_bounds__(256, 2)
void gemm_multi_kernel(const bf16* __restrict__ WKH, const bf16* __restrict__ WQHT,
                       const bf16* __restrict__ FCWT, const bf16* __restrict__ WVH,
                       bf16* __restrict__ WQKT, bf16* __restrict__ WVFT) {
    constexpr int KP = 320, NT = KP / BK;
    const int z = blockIdx.z, h = z & 1;
    const bf16 *A, *Bt; bf16* outB; int lda, ldo, Mreal, Nreal;
    if (z < 2) {
        if (blockIdx.x >= 2) return;
        A = WKH + (size_t)h*576*320;  lda = 320;
        Bt = WQHT + (size_t)h*352*320;
        outB = WQKT + (size_t)h*576*192; ldo = 192; Mreal = 576; Nreal = 192;
    } else {
        A = FCWT + (size_t)h*258;     lda = 576;
        Bt = WVH + (size_t)h*704*320;
        outB = WVFT + (size_t)h*576;  ldo = 1152; Mreal = 516; Nreal = 576;
    }
    __shared__ __align__(16) bf16 As[2][128][BK];
    __shared__ __align__(16) bf16 Bs[2][BN][BK];
    const int tid = threadIdx.x, w = tid >> 6, lane = tid & 63;
    const int lr = lane & 15, ls = lane >> 4;
    const int lrow = lane >> 3, lcol = (lane & 7) * 8;
    const bf16* aBase = A  + (size_t)(blockIdx.y * 128 + w * 32 + lrow) * lda + lcol;
    const bf16* bBase = Bt + (size_t)(blockIdx.x * BN + lrow) * KP + lcol;
    auto stage = [&](int buf, int k0) {
        #pragma unroll
        for (int i = 0; i < 4; ++i)
            gload16(aBase + (size_t)(i * 8) * lda + k0, &As[buf][w * 32 + i * 8][0]);
        #pragma unroll
        for (int jj = 0; jj < 6; ++jj) {
            int j = jj * 4 + w;
            if (j < 22) gload16(bBase + (size_t)(j * 8) * KP + k0, &Bs[buf][j * 8][0]);
        }
    };
    f32x4 acc[2][11];
    #pragma unroll
    for (int a = 0; a < 2; ++a)
        #pragma unroll
        for (int b2 = 0; b2 < 11; ++b2) acc[a][b2] = (f32x4)(0.0f);
    stage(0, 0);
    __syncthreads();
    int cur = 0;
    for (int t = 0; t < NT; ++t) {
        if (t + 1 < NT) stage(cur ^ 1, (t + 1) * BK);
        #pragma unroll
        for (int kk = 0; kk < 2; ++kk) {
            bf16x8 a0 = *(const bf16x8*)&As[cur][w*32 +      lr][kk*32 + ls*8];
            bf16x8 a1 = *(const bf16x8*)&As[cur][w*32 + 16 + lr][kk*32 + ls*8];
            #pragma unroll
            for (int nt = 0; nt < 11; ++nt) {
                bf16x8 bfr = *(const bf16x8*)&Bs[cur][nt*16 + lr][kk*32 + ls*8];
                acc[0][nt] = __builtin_amdgcn_mfma_f32_16x16x32_bf16(a0, bfr, acc[0][nt], 0, 0, 0);
                acc[1][nt] = __builtin_amdgcn_mfma_f32_16x16x32_bf16(a1, bfr, acc[1][nt], 0, 0, 0);
            }
        }
        __syncthreads();
        cur ^= 1;
    }
    const int colb = blockIdx.x * BN + lr;
    const int rowb = blockIdx.y * 128 + w*32 + ls*4;
    #pragma unroll
    for (int mt = 0; mt < 2; ++mt)
    #pragma unroll
    for (int nt = 0; nt < 11; ++nt)
    #pragma unroll
    for (int q2 = 0; q2 < 4; ++q2) {
        int row = rowb + mt*16 + q2;
        int col = colb + nt*16;
        if (row < Mreal && col < Nreal)
            outB[(size_t)row*ldo + col] = (bf16)acc[mt][nt][q2];
    }
}

// ---------------- attention-lite v8: v6 + QK preloaded to LDS ----------------
__global__ __launch_bounds__(256, 3)
void attn_lite_kernel(const bf16* __restrict__ QK, const bf16* __restrict__ nh16,
                      const float* __restrict__ edge_feat, const float* __restrict__ edge_t,
                      const int* __restrict__ nbr_idx, const float* __restrict__ freq,
                      const float* __restrict__ ph, const float* __restrict__ tnow,
                      bf16* __restrict__ ZB) {
    __shared__ __align__(16) bf16 zs[40 * 576];    // XOR-swizzled rows (pitch 1152 B)
    __shared__ __align__(16) bf16 qks[4 * 576];    // XOR-swizzled rows
    __shared__ __align__(16) float G[40][4];
    __shared__ float sfreq[172], sph[172];
    __shared__ float sdt[40];
    __shared__ int   ssrc[40];
    __shared__ float pp[2][20];

    const int r  = blockIdx.x;
    const int iA = 2 * r;
    const int t  = threadIdx.x;
    const int w  = t >> 6, lane = t & 63;
    const int lr = lane & 15, ls = lane >> 4;

    auto zsa = [&](int row, int c) -> bf16* {
        unsigned b = (unsigned)(row * 1152 + c * 2) ^ (unsigned)((row & 7) << 4);
        return (bf16*)((char*)zs + b);
    };
    auto qka = [&](int row, int c) -> bf16* {
        unsigned b = (unsigned)(row * 1152 + c * 2) ^ (unsigned)((row & 3) << 5);
        return (bf16*)((char*)qks + b);
    };

    // QK preload into LDS (independent of z-build; latency hides under it)
    #pragma unroll
    for (int s = 0; s < 2; ++s) {
        int idx = t + s * 256;
        if (idx < 288) {
            int m = idx / 72, g = idx % 72;
            *(bf16x8*)qka(m, g * 8) =
                *(const bf16x8*)(QK + (size_t)(iA + (m >> 1)) * 1152 + (m & 1) * 576 + g * 8);
        }
    }

    // Phase A: issue ef loads into static register slots (issue-early)
    f32x4 efA[4], efB[4];
    #pragma unroll
    for (int s = 0; s < 4; ++s) {
        int idx = t + (s + 3) * 256;
        if (idx >= 880 && idx < 1720) {
            int i2 = idx - 880;
            int row = i2 / 21, c = 22 + i2 % 21;
            const float* ep = edge_feat + (size_t)(iA * 20 + row) * 172 + (c * 8 - 172);
            efA[s] = *(const f32x4*)ep;
            efB[s] = *(const f32x4*)(ep + 4);
        }
    }

    if (t < 172) { sfreq[t] = freq[t]; sph[t] = ph[t]; }
    if (t >= 192 && t < 232) {
        int e2 = t - 192, ge = iA * 20 + e2;
        sdt[e2]  = tnow[0] - edge_t[ge];
        ssrc[e2] = nbr_idx[ge];
    }
    __syncthreads();

    // Phase B: nh segment + tenc/zero segments
    #pragma unroll
    for (int it = 0; it < 4; ++it) {
        int idx = t + it * 256;
        if (idx < 880) {
            int row = idx / 22, c = idx % 22;
            bf16x8 v;
            if (c < 21) {
                v = *(const bf16x8*)(nh16 + (size_t)ssrc[row] * 192 + c * 8);
            } else {
                int ge = iA * 20 + row;
                #pragma unroll
                for (int e = 0; e < 8; ++e) {
                    int k = 168 + e;
                    v[e] = (k < 172) ? nh16[(size_t)ssrc[row] * 192 + k]
                                     : (bf16)edge_feat[(size_t)ge * 172 + (k - 172)];
                }
            }
            *(bf16x8*)zsa(row, c * 8) = v;
        }
    }
    #pragma unroll
    for (int it = 6; it < 12; ++it) {
        int idx = t + it * 256;
        if (idx >= 1720 && idx < 2880) {
            int row, c;
            bf16x8 v;
            if (idx < 2600) {
                int i3 = idx - 1720;
                row = i3 / 22; c = 43 + i3 % 22;
                float dt = sdt[row];
                int k0 = c * 8;
                #pragma unroll
                for (int e = 0; e < 8; ++e) {
                    int k = k0 + e;
                    v[e] = (k < 516) ? (bf16)__cosf(dt * sfreq[k - 344] + sph[k - 344]) : (bf16)0.f;
                }
            } else {
                int i4 = idx - 2600;
                row = i4 / 7; c = 65 + i4 % 7;
                #pragma unroll
                for (int e = 0; e < 8; ++e) v[e] = (bf16)0.f;
            }
            *(bf16x8*)zsa(row, c * 8) = v;
        }
    }
    // Phase C: drain ef regs -> zs
    #pragma unroll
    for (int s = 0; s < 4; ++s) {
        int idx = t + (s + 3) * 256;
        if (idx >= 880 && idx < 1720) {
            int i2 = idx - 880;
            int row = i2 / 21, c = 22 + i2 % 21;
            bf16x8 v;
            #pragma unroll
            for (int e = 0; e < 4; ++e) { v[e] = (bf16)efA[s][e]; v[e+4] = (bf16)efB[s][e]; }
            *(bf16x8*)zsa(row, c * 8) = v;
        }
    }
    __syncthreads();

    // MFMA logits: G[4 x 40] = qks(4x576) . zs^T ; waves 0..2, A from LDS
    if (w < 3) {
        int brow = w * 16 + lr; if (brow > 39) brow = 39;
        f32x4 acc = (f32x4)(0.0f);
        __builtin_amdgcn_s_setprio(1);
        #pragma unroll
        for (int ks = 0; ks < 18; ++ks) {
            bf16x8 af = *(const bf16x8*)qka(lr & 3, ks * 32 + ls * 8);
            bf16x8 bf = *(const bf16x8*)zsa(brow, ks * 32 + ls * 8);
            acc = __builtin_amdgcn_mfma_f32_16x16x32_bf16(af, bf, acc, 0, 0, 0);
        }
        __builtin_amdgcn_s_setprio(0);
        int col = w * 16 + lr;
        if (ls == 0 && col < 40) *(f32x4*)&G[col][0] = acc;
    }
    __syncthreads();

    // wave-parallel softmax: wave 0, lane = h*32 + knbr
    if (t < 64) {
        int h = lane >> 5, knbr = lane & 31;
        bool act = knbr < 20;
        float l = -1e30f;
        if (act) {
            int z0 = (knbr / 10) * 20 + 2 * (knbr % 10);
            l = (G[z0][h] + G[z0 + 1][2 + h]) * 0.0622573006f;   // 1/sqrt(258)
        }
        float m = l;
        #pragma unroll
        for (int o = 16; o >= 1; o >>= 1) m = fmaxf(m, __shfl_xor(m, o));
        float e = act ? __expf(l - m) : 0.f;
        float s2 = e;
        #pragma unroll
        for (int o = 16; o >= 1; o >>= 1) s2 += __shfl_xor(s2, o);
        if (act) pp[h][knbr] = e / s2;
    }
    __syncthreads();

    // ZB: 288 tasks (nsel, 4-elem chunk); z read ONCE, both heads accumulated
    #pragma unroll
    for (int it = 0; it < 2; ++it) {
        int idx = t + it * 256;
        if (idx < 288) {
            int nsel = idx / 144, c4 = (idx % 144) * 4;
            float a0[4] = {0.f, 0.f, 0.f, 0.f};
            float a1[4] = {0.f, 0.f, 0.f, 0.f};
            #pragma unroll
            for (int knbr = 0; knbr < 20; ++knbr) {
                int z0 = (knbr / 10) * 20 + 2 * (knbr % 10) + nsel;
                bf16x4 zv = *(const bf16x4*)zsa(z0, c4);
                float p0 = pp[0][knbr], p1 = pp[1][knbr];
                #pragma unroll
                for (int i = 0; i < 4; ++i) {
                    float zf = (float)zv[i];
                    a0[i] += p0 * zf;
                    a1[i] += p1 * zf;
                }
            }
            bf16x4 o0, o1;
            #pragma unroll
            for (int i = 0; i < 4; ++i) { o0[i] = (bf16)a0[i]; o1[i] = (bf16)a1[i]; }
            *(bf16x4*)(ZB + (size_t)(iA + nsel) * 1152 + c4)       = o0;   // head 0
            *(bf16x4*)(ZB + (size_t)(iA + nsel) * 1152 + 576 + c4) = o1;   // head 1
        }
    }
}

// ---------------- LayerNorm + build X = [h_ln, node_h, 0pad] ----------------
__global__ __launch_bounds__(256)
void ln_x_kernel(const float* __restrict__ fcr, const float* __restrict__ g,
                 const float* __restrict__ b, const bf16* __restrict__ nh16,
                 bf16* __restrict__ X) {
    __shared__ float red[2][4];
    __shared__ float mb[2];
    const size_t i = blockIdx.x;
    const int t = threadIdx.x;
    int c0 = t, c1 = t + 256, c2 = t + 512;
    float v0 = fcr[i*516 + c0];
    float v1 = (c1 < 516) ? fcr[i*516 + c1] : 0.f;
    float v2 = (c2 < 516) ? fcr[i*516 + c2] : 0.f;
    float s = v0 + v1 + v2, ss = v0*v0 + v1*v1 + v2*v2;
    #pragma unroll
    for (int o = 32; o; o >>= 1) { s += __shfl_down(s, o); ss += __shfl_down(ss, o); }
    if ((t & 63) == 0) { red[0][t >> 6] = s; red[1][t >> 6] = ss; }
    __syncthreads();
    if (t == 0) {
        float S  = red[0][0] + red[0][1] + red[0][2] + red[0][3];
        float SS = red[1][0] + red[1][1] + red[1][2] + red[1][3];
        float mean = S / 516.f;
        float var  = SS / 516.f - mean*mean;
        mb[0] = mean; mb[1] = rsqrtf(var + 1e-5f);
    }
    __syncthreads();
    float mean = mb[0], rstd = mb[1];
    X[i*704 + c0] = (bf16)((v0 - mean)*rstd*g[c0] + b[c0]);
    if (c1 < 516) X[i*704 + c1] = (bf16)((v1 - mean)*rstd*g[c1] + b[c1]);
    if (c2 < 516) X[i*704 + c2] = (bf16)((v2 - mean)*rstd*g[c2] + b[c2]);
    for (int c = 516 + t; c < 704; c += 256)
        X[i*704 + c] = (c < 688) ? nh16[i*192 + (c - 516)] : (bf16)0.f;
}

// ---------------- launch ----------------
extern "C" void kernel_launch(void* const* d_in, const int* in_sizes, int n_in,
                              void* d_out, int out_size, void* d_ws, size_t ws_size,
                              hipStream_t stream) {
    const float* node_h     = (const float*)d_in[0];
    const float* edge_t     = (const float*)d_in[1];
    const float* edge_feat  = (const float*)d_in[2];
    const int*   nbr_idx    = (const int*)d_in[3];
    const float* t_now      = (const float*)d_in[4];
    const float* w_q        = (const float*)d_in[6];
    const float* w_k        = (const float*)d_in[7];
    const float* w_v        = (const float*)d_in[8];
    const float* basis_freq = (const float*)d_in[9];
    const float* phase      = (const float*)d_in[10];
    const float* ln_g       = (const float*)d_in[11];
    const float* ln_b       = (const float*)d_in[12];
    const float* fc_w       = (const float*)d_in[13];
    const float* fc_b       = (const float*)d_in[14];
    const float* m1_w       = (const float*)d_in[15];
    const float* m1_b       = (const float*)d_in[16];
    const float* m2_w       = (const float*)d_in[17];
    const float* m2_b       = (const float*)d_in[18];

    char* ws = (char*)d_ws;
    bf16*  FCWT = (bf16*)(ws + FCWT_OFF);
    bf16*  M1WT = (bf16*)(ws + M1WT_OFF);
    bf16*  M2WT = (bf16*)(ws + M2WT_OFF);
    bf16*  WKH  = (bf16*)(ws + WKH_OFF);
    bf16*  WQHT = (bf16*)(ws + WQHT_OFF);
    bf16*  WVH  = (bf16*)(ws + WVH_OFF);
    bf16*  WQKT = (bf16*)(ws + WQKT_OFF);
    bf16*  WVFT = (bf16*)(ws + WVFT_OFF);
    float* QB   = (float*)(ws + QB_OFF);
    float* QKB  = (float*)(ws + QKB_OFF);
    float* CPH  = (float*)(ws + CPH_OFF);
    bf16*  NH16 = (bf16*)(ws + NH16_OFF);
    bf16*  QK   = (bf16*)(ws + QK_OFF);
    bf16*  ZB   = (bf16*)(ws + ZB_OFF);
    float* FCR  = (float*)(ws + FCR_OFF);
    bf16*  Xb   = (bf16*)(ws + X_OFF);
    bf16*  Rb   = (bf16*)(ws + R_OFF);

    hipMemsetAsync(ws, 0, NH16_OFF, stream);

    packT_kernel<<<dim3(289, 3), 256, 0, stream>>>(fc_w, m1_w, m2_w, FCWT, M1WT, M2WT);
    pack_misc_kernel<<<2048, 256, 0, stream>>>(w_k, w_q, w_v, node_h, phase,
                                               WKH, WQHT, WVH, NH16, CPH, QB);
    qkb_kernel<<<1152, 256, 0, stream>>>(w_k, QB, QKB);

    // WQK^T (z=0,1) and WVF^T (z=2,3) in one launch
    gemm_multi_kernel<<<dim3(4, 5, 4), 256, 0, stream>>>(WKH, WQHT, FCWT, WVH, WQKT, WVFT);

    // qk = NH16 @ WQK^T + qkb   -> QK [NPAD][1152]   (BM=64, 2 blocks/CU)
    gemm_kernel<192, 0, 1><<<dim3(7, 158), 256, 0, stream>>>(
        NH16, 192, WQKT, nullptr, QK, 1152, QKB, nullptr, nullptr, NN, 1152);

    // attention -> ZB [NPAD][1152]
    attn_lite_kernel<<<NN / 2, 256, 0, stream>>>(
        QK, NH16, edge_feat, edge_t, nbr_idx, basis_freq, phase, t_now, ZB);

    // fcr = ZB @ WVF^T + fc_b + self_z   (BM=64)
    gemm_kernel<1152, 2, 1><<<dim3(3, 158), 256, 0, stream>>>(
        ZB, 1152, WVFT, FCR, nullptr, 516, fc_b, node_h, CPH, NN, 516);

    ln_x_kernel<<<NN, 256, 0, stream>>>(FCR, ln_g, ln_b, NH16, Xb);

    // m1 + relu  (BM=64; cols 172..175 zeroed so m2 A-loads are clean)
    gemm_kernel<704, 3, 1><<<dim3(1, 158), 256, 0, stream>>>(
        Xb, 704, M1WT, nullptr, Rb, 192, m1_b, nullptr, nullptr, NN, 172);

    // m2 -> out  (BM=64; K-pad rows of M2WT are zero so poison A cols are inert)
    gemm_kernel<192, 4, 1><<<dim3(1, 158), 256, 0, stream>>>(
        Rb, 192, M2WT, (float*)d_out, nullptr, 172, m2_b, nullptr, nullptr, NN, 172);
}

// Round 15
// 238.799 us; speedup vs baseline: 1.2013x; 1.2013x over previous
//
#include <hip/hip_runtime.h>
#include <hip/hip_bf16.h>
#include <math.h>

typedef __bf16 bf16;
typedef __attribute__((ext_vector_type(4))) __bf16 bf16x4;
typedef __attribute__((ext_vector_type(8))) __bf16 bf16x8;
typedef __attribute__((ext_vector_type(4))) float f32x4;

// ---------------- problem constants ----------------
constexpr int NN   = 10000;
constexpr int NPAD = 10112;            // 128-aligned (DMA overrun pad)
constexpr int BN = 176, BK = 64;

// ---------------- workspace layout (bytes) ----------------
constexpr size_t FCWT_OFF = 0;                         // bf16 [528][576]   fcw^T (zero-padded)
constexpr size_t M1WT_OFF = 608256;                    // bf16 [176][704]
constexpr size_t M2WT_OFF = 856064;                    // bf16 [176][192]
constexpr size_t WKH_OFF  = 923648;                    // bf16 [2*576][320] wk head-slices
constexpr size_t WQHT_OFF = 1660928;                   // bf16 [2*352][320] wq head-slices (rows<172)
constexpr size_t WVH_OFF  = 2111488;                   // bf16 [2*704][320] wv head-slices
constexpr size_t WQKT_OFF = 3012608;                   // bf16 [1232][192]  WQK^T (qk GEMM B)
constexpr size_t WVFT_OFF = 3485696;                   // bf16 [528][1152]  WVF^T (fusedFC B)
constexpr size_t QB_OFF   = 4702208;                   // f32 [516]
constexpr size_t QKB_OFF  = 4706304;                   // f32 [1232]
constexpr size_t CPH_OFF  = 4714496;                   // f32 [172]
constexpr size_t NH16_OFF = 4715520;                   // bf16 [NPAD][192]
constexpr size_t QK_OFF   = NH16_OFF + (size_t)NPAD*192*2;    // bf16 [NPAD][1152]
constexpr size_t ZB_OFF   = QK_OFF   + (size_t)NPAD*1152*2;   // bf16 [NPAD][1152]
constexpr size_t FCR_OFF  = ZB_OFF   + (size_t)NPAD*1152*2;   // f32 [NN][516]
constexpr size_t X_OFF    = FCR_OFF  + (size_t)NN*516*4;      // bf16 [NPAD][704]
constexpr size_t R_OFF    = X_OFF    + (size_t)NPAD*704*2;    // bf16 [NPAD][192]

// ---------------- global_load_lds helper (width 16) ----------------
typedef __attribute__((address_space(3))) void lds_void;
typedef const __attribute__((address_space(1))) void glb_void;
__device__ __forceinline__ void gload16(const void* g, void* l) {
    __builtin_amdgcn_global_load_lds((glb_void*)(uintptr_t)g,
                                     (lds_void*)(unsigned int)(uintptr_t)l, 16, 0, 0);
}

// ---------------- tiled transpose-pack (fcw, m1w, m2w) ----------------
__global__ __launch_bounds__(256)
void packT_kernel(const float* __restrict__ fcw, const float* __restrict__ m1w,
                  const float* __restrict__ m2w,
                  bf16* __restrict__ FCWT, bf16* __restrict__ M1WT, bf16* __restrict__ M2WT) {
    __shared__ float tile[32][33];
    const float* src; bf16* dst; int K, C, LD;
    switch (blockIdx.y) {
        case 0:  src = fcw; K = 516; C = 516; dst = FCWT; LD = 576; break;
        case 1:  src = m1w; K = 688; C = 172; dst = M1WT; LD = 704; break;
        default: src = m2w; K = 172; C = 172; dst = M2WT; LD = 192; break;
    }
    const int tilesC = (C + 31) >> 5, tilesK = (K + 31) >> 5;
    const int nt = tilesC * tilesK;
    const int tx = threadIdx.x & 31, ty = threadIdx.x >> 5;
    for (int tb = blockIdx.x; tb < nt; tb += gridDim.x) {
        int tc = tb % tilesC, tk = tb / tilesC;
        #pragma unroll
        for (int i = 0; i < 4; ++i) {
            int k = tk*32 + ty + i*8, c = tc*32 + tx;
            tile[ty + i*8][tx] = (k < K && c < C) ? src[(size_t)k*C + c] : 0.f;
        }
        __syncthreads();
        #pragma unroll
        for (int i = 0; i < 4; ++i) {
            int c = tc*32 + ty + i*8, k = tk*32 + tx;
            if (c < C && k < K) dst[(size_t)c*LD + k] = (bf16)tile[tx][ty + i*8];
        }
        __syncthreads();
    }
}

// ---------------- fused misc packs: wk/wq/wv head-slices + nh16 + cph ----------------
__global__ void pack_misc_kernel(const float* __restrict__ wk, const float* __restrict__ wq,
                                 const float* __restrict__ wv, const float* __restrict__ node_h,
                                 const float* __restrict__ phase,
                                 bf16* __restrict__ WKH, bf16* __restrict__ WQHT,
                                 bf16* __restrict__ WVH, bf16* __restrict__ nh16,
                                 float* __restrict__ cph) {
    constexpr int T0 = 2*516*258;
    constexpr int T1 = T0 + 2*172*258;
    constexpr int T2 = T1 + 2*516*258;
    constexpr int T3 = T2 + NN*192;
    constexpr int T4 = T3 + 172;
    for (int idx = blockIdx.x * blockDim.x + threadIdx.x; idx < T4;
         idx += gridDim.x * blockDim.x) {
        if (idx < T0) {
            int h = idx / (516*258), rem = idx % (516*258), d = rem / 258, j = rem % 258;
            WKH[((size_t)h*576 + d)*320 + j] = (bf16)wk[(size_t)d*516 + h*258 + j];
        } else if (idx < T1) {
            int i = idx - T0;
            int h = i / (172*258), rem = i % (172*258), k = rem / 258, j = rem % 258;
            WQHT[((size_t)h*352 + k)*320 + j] = (bf16)wq[(size_t)k*516 + h*258 + j];
        } else if (idx < T2) {
            int i = idx - T1;
            int h = i / (516*258), rem = i % (516*258), c = rem / 258, j = rem % 258;
            WVH[((size_t)h*704 + c)*320 + j] = (bf16)wv[(size_t)c*516 + h*258 + j];
        } else if (idx < T3) {
            int i = idx - T2, r = i / 192, c = i % 192;
            nh16[i] = (c < 172) ? (bf16)node_h[(size_t)r*172 + c] : (bf16)0.f;
        } else cph[idx - T3] = cosf(phase[idx - T3]);
    }
}

// QB[c] = sum_j cos(phase[j]) * w_q[(344+j)*516 + c] — one block per c, LDS reduce
__global__ __launch_bounds__(256)
void qbias_kernel(const float* __restrict__ w_q, const float* __restrict__ phase,
                  float* __restrict__ q_bias) {
    __shared__ float red[256];
    const int c = blockIdx.x, j = threadIdx.x;
    red[j] = (j < 172) ? cosf(phase[j]) * w_q[(size_t)(344 + j) * 516 + c] : 0.f;
    __syncthreads();
    #pragma unroll
    for (int o = 128; o; o >>= 1) { if (j < o) red[j] += red[j + o]; __syncthreads(); }
    if (j == 0) q_bias[c] = red[0];
}

// qkb[h*576+d] = sum_{j<258} QB[h*258+j] * wk[d][h*258+j]   (d<516, else 0)
__global__ __launch_bounds__(256)
void qkb_kernel(const float* __restrict__ wk, const float* __restrict__ QB,
                float* __restrict__ qkb) {
    __shared__ float red[256];
    const int hd = blockIdx.x, h = hd / 576, d = hd % 576, t = threadIdx.x;
    float a = 0.f;
    if (d < 516) {
        a = QB[h*258 + t] * wk[(size_t)d*516 + h*258 + t];
        if (t < 2) a += QB[h*258 + 256 + t] * wk[(size_t)d*516 + h*258 + 256 + t];
    }
    red[t] = a; __syncthreads();
    #pragma unroll
    for (int o = 128; o; o >>= 1) { if (t < o) red[t] += red[t + o]; __syncthreads(); }
    if (t == 0) qkb[hd] = red[0];
}

// ---------------- MFMA GEMM (DMA staging + 2-phase dbuf), MT row-tiles/wave ----------------
// EPI 0: bf16 out +bias   EPI 2: f32 out +bias +selfz   EPI 3: bf16 relu(+bias), 0 past Nreal
// EPI 4: f32 out +bias
template<int KP, int EPI, int MT>
__global__ __launch_bounds__(256, 2)
void gemm_kernel(const bf16* __restrict__ A, int lda, const bf16* __restrict__ Bt,
                 float* __restrict__ outF, bf16* __restrict__ outB, int ldo,
                 const float* __restrict__ bias,
                 const float* __restrict__ aux0, const float* __restrict__ aux1,
                 int Mreal, int Nreal) {
    constexpr int NT  = KP / BK;
    constexpr int BMt = 64 * MT;
    __shared__ __align__(16) bf16 As[2][BMt][BK];
    __shared__ __align__(16) bf16 Bs[2][BN][BK];

    const int tid  = threadIdx.x;
    const int w    = tid >> 6;
    const int lane = tid & 63;
    const int lr   = lane & 15;
    const int ls   = lane >> 4;
    const int lrow = lane >> 3;
    const int lcol = (lane & 7) * 8;

    const bf16* aBase = A  + (size_t)(blockIdx.y * BMt + w * 16 * MT + lrow) * lda + lcol;
    const bf16* bBase = Bt + (size_t)(blockIdx.x * BN + lrow) * KP + lcol;

    auto stage = [&](int buf, int k0) {
        #pragma unroll
        for (int i = 0; i < 2 * MT; ++i)
            gload16(aBase + (size_t)(i * 8) * lda + k0, &As[buf][w * 16 * MT + i * 8][0]);
        #pragma unroll
        for (int jj = 0; jj < 6; ++jj) {
            int j = jj * 4 + w;
            if (j < 22) gload16(bBase + (size_t)(j * 8) * KP + k0, &Bs[buf][j * 8][0]);
        }
    };

    f32x4 acc[MT][11];
    #pragma unroll
    for (int a = 0; a < MT; ++a)
        #pragma unroll
        for (int b2 = 0; b2 < 11; ++b2) acc[a][b2] = (f32x4)(0.0f);

    stage(0, 0);
    __syncthreads();
    int cur = 0;
    for (int t = 0; t < NT; ++t) {
        if (t + 1 < NT) stage(cur ^ 1, (t + 1) * BK);
        #pragma unroll
        for (int kk = 0; kk < 2; ++kk) {
            bf16x8 afr[MT];
            #pragma unroll
            for (int mt = 0; mt < MT; ++mt)
                afr[mt] = *(const bf16x8*)&As[cur][w*16*MT + mt*16 + lr][kk*32 + ls*8];
            #pragma unroll
            for (int nt = 0; nt < 11; ++nt) {
                bf16x8 bfr = *(const bf16x8*)&Bs[cur][nt*16 + lr][kk*32 + ls*8];
                #pragma unroll
                for (int mt = 0; mt < MT; ++mt)
                    acc[mt][nt] = __builtin_amdgcn_mfma_f32_16x16x32_bf16(afr[mt], bfr, acc[mt][nt], 0, 0, 0);
            }
        }
        __syncthreads();
        cur ^= 1;
    }

    const int colb = blockIdx.x * BN + lr;
    const int rowb = blockIdx.y * BMt + w*16*MT + ls*4;
    #pragma unroll
    for (int mt = 0; mt < MT; ++mt)
    #pragma unroll
    for (int nt = 0; nt < 11; ++nt)
    #pragma unroll
    for (int q2 = 0; q2 < 4; ++q2) {
        int row = rowb + mt*16 + q2;
        int col = colb + nt*16;
        if (row >= Mreal) continue;
        float v = acc[mt][nt][q2];
        if constexpr (EPI == 0) {
            if (col < Nreal) outB[(size_t)row*ldo + col] = (bf16)(v + bias[col]);
        } else if constexpr (EPI == 2) {
            if (col < Nreal) {
                float sz = (col < 172) ? aux0[(size_t)row*172 + col]
                                       : ((col < 344) ? 0.f : aux1[col - 344]);
                outF[(size_t)row*ldo + col] = v + bias[col] + sz;
            }
        } else if constexpr (EPI == 3) {
            float vv = (col < Nreal) ? fmaxf(v + bias[col], 0.f) : 0.f;
            outB[(size_t)row*ldo + col] = (bf16)vv;
        } else {
            if (col < Nreal) outF[(size_t)row*ldo + col] = v + bias[col];
        }
    }
}

// ---------------- combined WQK/WVF GEMMs (KP=320, bf16 plain out), blockIdx.z selects ----------------
__global__ __launch_bounds__(256, 2)
void gemm_multi_kernel(const bf16* __restrict__ WKH, const bf16* __restrict__ WQHT,
                       const bf16* __restrict__ FCWT, const bf16* __restrict__ WVH,
                       bf16* __restrict__ WQKT, bf16* __restrict__ WVFT) {
    constexpr int KP = 320, NT = KP / BK;
    const int z = blockIdx.z, h = z & 1;
    const bf16 *A, *Bt; bf16* outB; int lda, ldo, Mreal, Nreal;
    if (z < 2) {
        if (blockIdx.x >= 2) return;
        A = WKH + (size_t)h*576*320;  lda = 320;
        Bt = WQHT + (size_t)h*352*320;
        outB = WQKT + (size_t)h*576*192; ldo = 192; Mreal = 576; Nreal = 192;
    } else {
        A = FCWT + (size_t)h*258;     lda = 576;
        Bt = WVH + (size_t)h*704*320;
        outB = WVFT + (size_t)h*576;  ldo = 1152; Mreal = 516; Nreal = 576;
    }
    __shared__ __align__(16) bf16 As[2][128][BK];
    __shared__ __align__(16) bf16 Bs[2][BN][BK];
    const int tid = threadIdx.x, w = tid >> 6, lane = tid & 63;
    const int lr = lane & 15, ls = lane >> 4;
    const int lrow = lane >> 3, lcol = (lane & 7) * 8;
    const bf16* aBase = A  + (size_t)(blockIdx.y * 128 + w * 32 + lrow) * lda + lcol;
    const bf16* bBase = Bt + (size_t)(blockIdx.x * BN + lrow) * KP + lcol;
    auto stage = [&](int buf, int k0) {
        #pragma unroll
        for (int i = 0; i < 4; ++i)
            gload16(aBase + (size_t)(i * 8) * lda + k0, &As[buf][w * 32 + i * 8][0]);
        #pragma unroll
        for (int jj = 0; jj < 6; ++jj) {
            int j = jj * 4 + w;
            if (j < 22) gload16(bBase + (size_t)(j * 8) * KP + k0, &Bs[buf][j * 8][0]);
        }
    };
    f32x4 acc[2][11];
    #pragma unroll
    for (int a = 0; a < 2; ++a)
        #pragma unroll
        for (int b2 = 0; b2 < 11; ++b2) acc[a][b2] = (f32x4)(0.0f);
    stage(0, 0);
    __syncthreads();
    int cur = 0;
    for (int t = 0; t < NT; ++t) {
        if (t + 1 < NT) stage(cur ^ 1, (t + 1) * BK);
        #pragma unroll
        for (int kk = 0; kk < 2; ++kk) {
            bf16x8 a0 = *(const bf16x8*)&As[cur][w*32 +      lr][kk*32 + ls*8];
            bf16x8 a1 = *(const bf16x8*)&As[cur][w*32 + 16 + lr][kk*32 + ls*8];
            #pragma unroll
            for (int nt = 0; nt < 11; ++nt) {
                bf16x8 bfr = *(const bf16x8*)&Bs[cur][nt*16 + lr][kk*32 + ls*8];
                acc[0][nt] = __builtin_amdgcn_mfma_f32_16x16x32_bf16(a0, bfr, acc[0][nt], 0, 0, 0);
                acc[1][nt] = __builtin_amdgcn_mfma_f32_16x16x32_bf16(a1, bfr, acc[1][nt], 0, 0, 0);
            }
        }
        __syncthreads();
        cur ^= 1;
    }
    const int colb = blockIdx.x * BN + lr;
    const int rowb = blockIdx.y * 128 + w*32 + ls*4;
    #pragma unroll
    for (int mt = 0; mt < 2; ++mt)
    #pragma unroll
    for (int nt = 0; nt < 11; ++nt)
    #pragma unroll
    for (int q2 = 0; q2 < 4; ++q2) {
        int row = rowb + mt*16 + q2;
        int col = colb + nt*16;
        if (row < Mreal && col < Nreal)
            outB[(size_t)row*ldo + col] = (bf16)acc[mt][nt][q2];
    }
}

// ---------------- attention-lite v8: QK preloaded to LDS (R14, measured 104 us) ----------------
__global__ __launch_bounds__(256, 3)
void attn_lite_kernel(const bf16* __restrict__ QK, const bf16* __restrict__ nh16,
                      const float* __restrict__ edge_feat, const float* __restrict__ edge_t,
                      const int* __restrict__ nbr_idx, const float* __restrict__ freq,
                      const float* __restrict__ ph, const float* __restrict__ tnow,
                      bf16* __restrict__ ZB) {
    __shared__ __align__(16) bf16 zs[40 * 576];    // XOR-swizzled rows (pitch 1152 B)
    __shared__ __align__(16) bf16 qks[4 * 576];    // XOR-swizzled rows
    __shared__ __align__(16) float G[40][4];
    __shared__ float sfreq[172], sph[172];
    __shared__ float sdt[40];
    __shared__ int   ssrc[40];
    __shared__ float pp[2][20];

    const int r  = blockIdx.x;
    const int iA = 2 * r;
    const int t  = threadIdx.x;
    const int w  = t >> 6, lane = t & 63;
    const int lr = lane & 15, ls = lane >> 4;

    auto zsa = [&](int row, int c) -> bf16* {
        unsigned b = (unsigned)(row * 1152 + c * 2) ^ (unsigned)((row & 7) << 4);
        return (bf16*)((char*)zs + b);
    };
    auto qka = [&](int row, int c) -> bf16* {
        unsigned b = (unsigned)(row * 1152 + c * 2) ^ (unsigned)((row & 3) << 5);
        return (bf16*)((char*)qks + b);
    };

    // QK preload into LDS (latency hides under z-build)
    #pragma unroll
    for (int s = 0; s < 2; ++s) {
        int idx = t + s * 256;
        if (idx < 288) {
            int m = idx / 72, g = idx % 72;
            *(bf16x8*)qka(m, g * 8) =
                *(const bf16x8*)(QK + (size_t)(iA + (m >> 1)) * 1152 + (m & 1) * 576 + g * 8);
        }
    }

    // Phase A: issue ef loads into static register slots (issue-early)
    f32x4 efA[4], efB[4];
    #pragma unroll
    for (int s = 0; s < 4; ++s) {
        int idx = t + (s + 3) * 256;
        if (idx >= 880 && idx < 1720) {
            int i2 = idx - 880;
            int row = i2 / 21, c = 22 + i2 % 21;
            const float* ep = edge_feat + (size_t)(iA * 20 + row) * 172 + (c * 8 - 172);
            efA[s] = *(const f32x4*)ep;
            efB[s] = *(const f32x4*)(ep + 4);
        }
    }

    if (t < 172) { sfreq[t] = freq[t]; sph[t] = ph[t]; }
    if (t >= 192 && t < 232) {
        int e2 = t - 192, ge = iA * 20 + e2;
        sdt[e2]  = tnow[0] - edge_t[ge];
        ssrc[e2] = nbr_idx[ge];
    }
    __syncthreads();

    // Phase B: nh segment + tenc/zero segments
    #pragma unroll
    for (int it = 0; it < 4; ++it) {
        int idx = t + it * 256;
        if (idx < 880) {
            int row = idx / 22, c = idx % 22;
            bf16x8 v;
            if (c < 21) {
                v = *(const bf16x8*)(nh16 + (size_t)ssrc[row] * 192 + c * 8);
            } else {
                int ge = iA * 20 + row;
                #pragma unroll
                for (int e = 0; e < 8; ++e) {
                    int k = 168 + e;
                    v[e] = (k < 172) ? nh16[(size_t)ssrc[row] * 192 + k]
                                     : (bf16)edge_feat[(size_t)ge * 172 + (k - 172)];
                }
            }
            *(bf16x8*)zsa(row, c * 8) = v;
        }
    }
    #pragma unroll
    for (int it = 6; it < 12; ++it) {
        int idx = t + it * 256;
        if (idx >= 1720 && idx < 2880) {
            int row, c;
            bf16x8 v;
            if (idx < 2600) {
                int i3 = idx - 1720;
                row = i3 / 22; c = 43 + i3 % 22;
                float dt = sdt[row];
                int k0 = c * 8;
                #pragma unroll
                for (int e = 0; e < 8; ++e) {
                    int k = k0 + e;
                    v[e] = (k < 516) ? (bf16)__cosf(dt * sfreq[k - 344] + sph[k - 344]) : (bf16)0.f;
                }
            } else {
                int i4 = idx - 2600;
                row = i4 / 7; c = 65 + i4 % 7;
                #pragma unroll
                for (int e = 0; e < 8; ++e) v[e] = (bf16)0.f;
            }
            *(bf16x8*)zsa(row, c * 8) = v;
        }
    }
    // Phase C: drain ef regs -> zs
    #pragma unroll
    for (int s = 0; s < 4; ++s) {
        int idx = t + (s + 3) * 256;
        if (idx >= 880 && idx < 1720) {
            int i2 = idx - 880;
            int row = i2 / 21, c = 22 + i2 % 21;
            bf16x8 v;
            #pragma unroll
            for (int e = 0; e < 4; ++e) { v[e] = (bf16)efA[s][e]; v[e+4] = (bf16)efB[s][e]; }
            *(bf16x8*)zsa(row, c * 8) = v;
        }
    }
    __syncthreads();

    // MFMA logits: G[4 x 40] = qks(4x576) . zs^T ; waves 0..2, A from LDS
    if (w < 3) {
        int brow = w * 16 + lr; if (brow > 39) brow = 39;
        f32x4 acc = (f32x4)(0.0f);
        __builtin_amdgcn_s_setprio(1);
        #pragma unroll
        for (int ks = 0; ks < 18; ++ks) {
            bf16x8 af = *(const bf16x8*)qka(lr & 3, ks * 32 + ls * 8);
            bf16x8 bf = *(const bf16x8*)zsa(brow, ks * 32 + ls * 8);
            acc = __builtin_amdgcn_mfma_f32_16x16x32_bf16(af, bf, acc, 0, 0, 0);
        }
        __builtin_amdgcn_s_setprio(0);
        int col = w * 16 + lr;
        if (ls == 0 && col < 40) *(f32x4*)&G[col][0] = acc;
    }
    __syncthreads();

    // wave-parallel softmax: wave 0, lane = h*32 + knbr
    if (t < 64) {
        int h = lane >> 5, knbr = lane & 31;
        bool act = knbr < 20;
        float l = -1e30f;
        if (act) {
            int z0 = (knbr / 10) * 20 + 2 * (knbr % 10);
            l = (G[z0][h] + G[z0 + 1][2 + h]) * 0.0622573006f;   // 1/sqrt(258)
        }
        float m = l;
        #pragma unroll
        for (int o = 16; o >= 1; o >>= 1) m = fmaxf(m, __shfl_xor(m, o));
        float e = act ? __expf(l - m) : 0.f;
        float s2 = e;
        #pragma unroll
        for (int o = 16; o >= 1; o >>= 1) s2 += __shfl_xor(s2, o);
        if (act) pp[h][knbr] = e / s2;
    }
    __syncthreads();

    // ZB: 288 tasks (nsel, 4-elem chunk); z read ONCE, both heads accumulated
    #pragma unroll
    for (int it = 0; it < 2; ++it) {
        int idx = t + it * 256;
        if (idx < 288) {
            int nsel = idx / 144, c4 = (idx % 144) * 4;
            float a0[4] = {0.f, 0.f, 0.f, 0.f};
            float a1[4] = {0.f, 0.f, 0.f, 0.f};
            #pragma unroll
            for (int knbr = 0; knbr < 20; ++knbr) {
                int z0 = (knbr / 10) * 20 + 2 * (knbr % 10) + nsel;
                bf16x4 zv = *(const bf16x4*)zsa(z0, c4);
                float p0 = pp[0][knbr], p1 = pp[1][knbr];
                #pragma unroll
                for (int i = 0; i < 4; ++i) {
                    float zf = (float)zv[i];
                    a0[i] += p0 * zf;
                    a1[i] += p1 * zf;
                }
            }
            bf16x4 o0, o1;
            #pragma unroll
            for (int i = 0; i < 4; ++i) { o0[i] = (bf16)a0[i]; o1[i] = (bf16)a1[i]; }
            *(bf16x4*)(ZB + (size_t)(iA + nsel) * 1152 + c4)       = o0;   // head 0
            *(bf16x4*)(ZB + (size_t)(iA + nsel) * 1152 + 576 + c4) = o1;   // head 1
        }
    }
}

// ---------------- LayerNorm + build X = [h_ln, node_h, 0pad] ----------------
__global__ __launch_bounds__(256)
void ln_x_kernel(const float* __restrict__ fcr, const float* __restrict__ g,
                 const float* __restrict__ b, const bf16* __restrict__ nh16,
                 bf16* __restrict__ X) {
    __shared__ float red[2][4];
    __shared__ float mb[2];
    const size_t i = blockIdx.x;
    const int t = threadIdx.x;
    int c0 = t, c1 = t + 256, c2 = t + 512;
    float v0 = fcr[i*516 + c0];
    float v1 = (c1 < 516) ? fcr[i*516 + c1] : 0.f;
    float v2 = (c2 < 516) ? fcr[i*516 + c2] : 0.f;
    float s = v0 + v1 + v2, ss = v0*v0 + v1*v1 + v2*v2;
    #pragma unroll
    for (int o = 32; o; o >>= 1) { s += __shfl_down(s, o); ss += __shfl_down(ss, o); }
    if ((t & 63) == 0) { red[0][t >> 6] = s; red[1][t >> 6] = ss; }
    __syncthreads();
    if (t == 0) {
        float S  = red[0][0] + red[0][1] + red[0][2] + red[0][3];
        float SS = red[1][0] + red[1][1] + red[1][2] + red[1][3];
        float mean = S / 516.f;
        float var  = SS / 516.f - mean*mean;
        mb[0] = mean; mb[1] = rsqrtf(var + 1e-5f);
    }
    __syncthreads();
    float mean = mb[0], rstd = mb[1];
    X[i*704 + c0] = (bf16)((v0 - mean)*rstd*g[c0] + b[c0]);
    if (c1 < 516) X[i*704 + c1] = (bf16)((v1 - mean)*rstd*g[c1] + b[c1]);
    if (c2 < 516) X[i*704 + c2] = (bf16)((v2 - mean)*rstd*g[c2] + b[c2]);
    for (int c = 516 + t; c < 704; c += 256)
        X[i*704 + c] = (c < 688) ? nh16[i*192 + (c - 516)] : (bf16)0.f;
}

// ---------------- launch ----------------
extern "C" void kernel_launch(void* const* d_in, const int* in_sizes, int n_in,
                              void* d_out, int out_size, void* d_ws, size_t ws_size,
                              hipStream_t stream) {
    const float* node_h     = (const float*)d_in[0];
    const float* edge_t     = (const float*)d_in[1];
    const float* edge_feat  = (const float*)d_in[2];
    const int*   nbr_idx    = (const int*)d_in[3];
    const float* t_now      = (const float*)d_in[4];
    const float* w_q        = (const float*)d_in[6];
    const float* w_k        = (const float*)d_in[7];
    const float* w_v        = (const float*)d_in[8];
    const float* basis_freq = (const float*)d_in[9];
    const float* phase      = (const float*)d_in[10];
    const float* ln_g       = (const float*)d_in[11];
    const float* ln_b       = (const float*)d_in[12];
    const float* fc_w       = (const float*)d_in[13];
    const float* fc_b       = (const float*)d_in[14];
    const float* m1_w       = (const float*)d_in[15];
    const float* m1_b       = (const float*)d_in[16];
    const float* m2_w       = (const float*)d_in[17];
    const float* m2_b       = (const float*)d_in[18];

    char* ws = (char*)d_ws;
    bf16*  FCWT = (bf16*)(ws + FCWT_OFF);
    bf16*  M1WT = (bf16*)(ws + M1WT_OFF);
    bf16*  M2WT = (bf16*)(ws + M2WT_OFF);
    bf16*  WKH  = (bf16*)(ws + WKH_OFF);
    bf16*  WQHT = (bf16*)(ws + WQHT_OFF);
    bf16*  WVH  = (bf16*)(ws + WVH_OFF);
    bf16*  WQKT = (bf16*)(ws + WQKT_OFF);
    bf16*  WVFT = (bf16*)(ws + WVFT_OFF);
    float* QB   = (float*)(ws + QB_OFF);
    float* QKB  = (float*)(ws + QKB_OFF);
    float* CPH  = (float*)(ws + CPH_OFF);
    bf16*  NH16 = (bf16*)(ws + NH16_OFF);
    bf16*  QK   = (bf16*)(ws + QK_OFF);
    bf16*  ZB   = (bf16*)(ws + ZB_OFF);
    float* FCR  = (float*)(ws + FCR_OFF);
    bf16*  Xb   = (bf16*)(ws + X_OFF);
    bf16*  Rb   = (bf16*)(ws + R_OFF);

    hipMemsetAsync(ws, 0, NH16_OFF, stream);

    packT_kernel<<<dim3(289, 3), 256, 0, stream>>>(fc_w, m1_w, m2_w, FCWT, M1WT, M2WT);
    pack_misc_kernel<<<2048, 256, 0, stream>>>(w_k, w_q, w_v, node_h, phase,
                                               WKH, WQHT, WVH, NH16, CPH);
    qbias_kernel<<<516, 256, 0, stream>>>(w_q, phase, QB);
    qkb_kernel<<<1152, 256, 0, stream>>>(w_k, QB, QKB);

    // WQK^T (z=0,1) and WVF^T (z=2,3) in one launch
    gemm_multi_kernel<<<dim3(4, 5, 4), 256, 0, stream>>>(WKH, WQHT, FCWT, WVH, WQKT, WVFT);

    // qk = NH16 @ WQK^T + qkb   -> QK [NPAD][1152]   (BM=64, 2 blocks/CU)
    gemm_kernel<192, 0, 1><<<dim3(7, 158), 256, 0, stream>>>(
        NH16, 192, WQKT, nullptr, QK, 1152, QKB, nullptr, nullptr, NN, 1152);

    // attention -> ZB [NPAD][1152]
    attn_lite_kernel<<<NN / 2, 256, 0, stream>>>(
        QK, NH16, edge_feat, edge_t, nbr_idx, basis_freq, phase, t_now, ZB);

    // fcr = ZB @ WVF^T + fc_b + self_z   (BM=64)
    gemm_kernel<1152, 2, 1><<<dim3(3, 158), 256, 0, stream>>>(
        ZB, 1152, WVFT, FCR, nullptr, 516, fc_b, node_h, CPH, NN, 516);

    ln_x_kernel<<<NN, 256, 0, stream>>>(FCR, ln_g, ln_b, NH16, Xb);

    // m1 + relu  (BM=64; cols 172..175 zeroed so m2 A-loads are clean)
    gemm_kernel<704, 3, 1><<<dim3(1, 158), 256, 0, stream>>>(
        Xb, 704, M1WT, nullptr, Rb, 192, m1_b, nullptr, nullptr, NN, 172);

    // m2 -> out  (BM=64; K-pad rows of M2WT are zero so poison A cols are inert)
    gemm_kernel<192, 4, 1><<<dim3(1, 158), 256, 0, stream>>>(
        Rb, 192, M2WT, (float*)d_out, nullptr, 172, m2_b, nullptr, nullptr, NN, 172);
}

// Round 16
// 234.569 us; speedup vs baseline: 1.2230x; 1.0180x over previous
//
#include <hip/hip_runtime.h>
#include <hip/hip_bf16.h>
#include <math.h>

typedef __bf16 bf16;
typedef __attribute__((ext_vector_type(4))) __bf16 bf16x4;
typedef __attribute__((ext_vector_type(8))) __bf16 bf16x8;
typedef __attribute__((ext_vector_type(4))) float f32x4;

// ---------------- problem constants ----------------
constexpr int NN   = 10000;
constexpr int NPAD = 10112;            // 128-aligned (DMA overrun pad)
constexpr int BN = 176, BK = 64;

// ---------------- workspace layout (bytes) ----------------
constexpr size_t FCWT_OFF = 0;                         // bf16 [528][576]   fcw^T (zero-padded)
constexpr size_t M1WT_OFF = 608256;                    // bf16 [176][704]
constexpr size_t M2WT_OFF = 856064;                    // bf16 [176][192]
constexpr size_t WKH_OFF  = 923648;                    // bf16 [2*576][320] wk head-slices
constexpr size_t WQHT_OFF = 1660928;                   // bf16 [2*352][320] wq head-slices (rows<172)
constexpr size_t WVH_OFF  = 2111488;                   // bf16 [2*704][320] wv head-slices
constexpr size_t WQKT_OFF = 3012608;                   // bf16 [1232][192]  WQK^T (qk GEMM B)
constexpr size_t WVFT_OFF = 3485696;                   // bf16 [528][1152]  WVF^T (fusedFC B)
constexpr size_t QB_OFF   = 4702208;                   // f32 [516]
constexpr size_t QKB_OFF  = 4706304;                   // f32 [1232]
constexpr size_t CPH_OFF  = 4714496;                   // f32 [172]
constexpr size_t NH16_OFF = 4715520;                   // bf16 [NPAD][192]
constexpr size_t QK_OFF   = NH16_OFF + (size_t)NPAD*192*2;    // bf16 [NPAD][1152]
constexpr size_t ZB_OFF   = QK_OFF   + (size_t)NPAD*1152*2;   // bf16 [NPAD][1152]
constexpr size_t FCR_OFF  = ZB_OFF   + (size_t)NPAD*1152*2;   // f32 [NN][516]
constexpr size_t X_OFF    = FCR_OFF  + (size_t)NN*516*4;      // bf16 [NPAD][704]
constexpr size_t R_OFF    = X_OFF    + (size_t)NPAD*704*2;    // bf16 [NPAD][192]

// ---------------- global_load_lds helper (width 16) ----------------
typedef __attribute__((address_space(3))) void lds_void;
typedef const __attribute__((address_space(1))) void glb_void;
__device__ __forceinline__ void gload16(const void* g, void* l) {
    __builtin_amdgcn_global_load_lds((glb_void*)(uintptr_t)g,
                                     (lds_void*)(unsigned int)(uintptr_t)l, 16, 0, 0);
}

// ---------------- fused prep: transpose-packs + misc packs + qbias ----------------
// y = 0..2: tiled transpose-pack (fcw, m1w, m2w)
// y = 3   : grid-stride pack of wk/wq/wv head-slices + nh16 + cph
// y = 4   : qbias (blockIdx.x < 516)
__global__ __launch_bounds__(256)
void prep_all_kernel(const float* __restrict__ fcw, const float* __restrict__ m1w,
                     const float* __restrict__ m2w, const float* __restrict__ wk,
                     const float* __restrict__ wq, const float* __restrict__ wv,
                     const float* __restrict__ node_h, const float* __restrict__ phase,
                     bf16* __restrict__ FCWT, bf16* __restrict__ M1WT, bf16* __restrict__ M2WT,
                     bf16* __restrict__ WKH, bf16* __restrict__ WQHT, bf16* __restrict__ WVH,
                     bf16* __restrict__ nh16, float* __restrict__ cph, float* __restrict__ QB) {
    const int y = blockIdx.y;
    if (y < 3) {
        __shared__ float tile[32][33];
        const float* src; bf16* dst; int K, C, LD;
        switch (y) {
            case 0:  src = fcw; K = 516; C = 516; dst = FCWT; LD = 576; break;
            case 1:  src = m1w; K = 688; C = 172; dst = M1WT; LD = 704; break;
            default: src = m2w; K = 172; C = 172; dst = M2WT; LD = 192; break;
        }
        const int tilesC = (C + 31) >> 5, tilesK = (K + 31) >> 5;
        const int nt = tilesC * tilesK;
        const int tx = threadIdx.x & 31, ty = threadIdx.x >> 5;
        for (int tb = blockIdx.x; tb < nt; tb += gridDim.x) {
            int tc = tb % tilesC, tk = tb / tilesC;
            #pragma unroll
            for (int i = 0; i < 4; ++i) {
                int k = tk*32 + ty + i*8, c = tc*32 + tx;
                tile[ty + i*8][tx] = (k < K && c < C) ? src[(size_t)k*C + c] : 0.f;
            }
            __syncthreads();
            #pragma unroll
            for (int i = 0; i < 4; ++i) {
                int c = tc*32 + ty + i*8, k = tk*32 + tx;
                if (c < C && k < K) dst[(size_t)c*LD + k] = (bf16)tile[tx][ty + i*8];
            }
            __syncthreads();
        }
    } else if (y == 3) {
        constexpr int T0 = 2*516*258;
        constexpr int T1 = T0 + 2*172*258;
        constexpr int T2 = T1 + 2*516*258;
        constexpr int T3 = T2 + NN*192;
        constexpr int T4 = T3 + 172;
        for (int idx = blockIdx.x * blockDim.x + threadIdx.x; idx < T4;
             idx += gridDim.x * blockDim.x) {
            if (idx < T0) {
                int h = idx / (516*258), rem = idx % (516*258), d = rem / 258, j = rem % 258;
                WKH[((size_t)h*576 + d)*320 + j] = (bf16)wk[(size_t)d*516 + h*258 + j];
            } else if (idx < T1) {
                int i = idx - T0;
                int h = i / (172*258), rem = i % (172*258), k = rem / 258, j = rem % 258;
                WQHT[((size_t)h*352 + k)*320 + j] = (bf16)wq[(size_t)k*516 + h*258 + j];
            } else if (idx < T2) {
                int i = idx - T1;
                int h = i / (516*258), rem = i % (516*258), c = rem / 258, j = rem % 258;
                WVH[((size_t)h*704 + c)*320 + j] = (bf16)wv[(size_t)c*516 + h*258 + j];
            } else if (idx < T3) {
                int i = idx - T2, r = i / 192, c = i % 192;
                nh16[i] = (c < 172) ? (bf16)node_h[(size_t)r*172 + c] : (bf16)0.f;
            } else cph[idx - T3] = cosf(phase[idx - T3]);
        }
    } else {
        if (blockIdx.x >= 516) return;
        __shared__ float red[256];
        const int c = blockIdx.x, j = threadIdx.x;
        red[j] = (j < 172) ? cosf(phase[j]) * wq[(size_t)(344 + j) * 516 + c] : 0.f;
        __syncthreads();
        #pragma unroll
        for (int o = 128; o; o >>= 1) { if (j < o) red[j] += red[j + o]; __syncthreads(); }
        if (j == 0) QB[c] = red[0];
    }
}

// qkb[h*576+d] = sum_{j<258} QB[h*258+j] * wk[d][h*258+j]   (d<516, else 0)
__global__ __launch_bounds__(256)
void qkb_kernel(const float* __restrict__ wk, const float* __restrict__ QB,
                float* __restrict__ qkb) {
    __shared__ float red[256];
    const int hd = blockIdx.x, h = hd / 576, d = hd % 576, t = threadIdx.x;
    float a = 0.f;
    if (d < 516) {
        a = QB[h*258 + t] * wk[(size_t)d*516 + h*258 + t];
        if (t < 2) a += QB[h*258 + 256 + t] * wk[(size_t)d*516 + h*258 + 256 + t];
    }
    red[t] = a; __syncthreads();
    #pragma unroll
    for (int o = 128; o; o >>= 1) { if (t < o) red[t] += red[t + o]; __syncthreads(); }
    if (t == 0) qkb[hd] = red[0];
}

// ---------------- MFMA GEMM (DMA staging + 2-phase dbuf), MT row-tiles/wave ----------------
// EPI 0: bf16 out +bias   EPI 2: f32 out +bias +selfz   EPI 3: bf16 relu(+bias), 0 past Nreal
// EPI 4: f32 out +bias
template<int KP, int EPI, int MT>
__global__ __launch_bounds__(256, 2)
void gemm_kernel(const bf16* __restrict__ A, int lda, const bf16* __restrict__ Bt,
                 float* __restrict__ outF, bf16* __restrict__ outB, int ldo,
                 const float* __restrict__ bias,
                 const float* __restrict__ aux0, const float* __restrict__ aux1,
                 int Mreal, int Nreal) {
    constexpr int NT  = KP / BK;
    constexpr int BMt = 64 * MT;
    __shared__ __align__(16) bf16 As[2][BMt][BK];
    __shared__ __align__(16) bf16 Bs[2][BN][BK];

    const int tid  = threadIdx.x;
    const int w    = tid >> 6;
    const int lane = tid & 63;
    const int lr   = lane & 15;
    const int ls   = lane >> 4;
    const int lrow = lane >> 3;
    const int lcol = (lane & 7) * 8;

    const bf16* aBase = A  + (size_t)(blockIdx.y * BMt + w * 16 * MT + lrow) * lda + lcol;
    const bf16* bBase = Bt + (size_t)(blockIdx.x * BN + lrow) * KP + lcol;

    auto stage = [&](int buf, int k0) {
        #pragma unroll
        for (int i = 0; i < 2 * MT; ++i)
            gload16(aBase + (size_t)(i * 8) * lda + k0, &As[buf][w * 16 * MT + i * 8][0]);
        #pragma unroll
        for (int jj = 0; jj < 6; ++jj) {
            int j = jj * 4 + w;
            if (j < 22) gload16(bBase + (size_t)(j * 8) * KP + k0, &Bs[buf][j * 8][0]);
        }
    };

    f32x4 acc[MT][11];
    #pragma unroll
    for (int a = 0; a < MT; ++a)
        #pragma unroll
        for (int b2 = 0; b2 < 11; ++b2) acc[a][b2] = (f32x4)(0.0f);

    stage(0, 0);
    __syncthreads();
    int cur = 0;
    for (int t = 0; t < NT; ++t) {
        if (t + 1 < NT) stage(cur ^ 1, (t + 1) * BK);
        #pragma unroll
        for (int kk = 0; kk < 2; ++kk) {
            bf16x8 afr[MT];
            #pragma unroll
            for (int mt = 0; mt < MT; ++mt)
                afr[mt] = *(const bf16x8*)&As[cur][w*16*MT + mt*16 + lr][kk*32 + ls*8];
            #pragma unroll
            for (int nt = 0; nt < 11; ++nt) {
                bf16x8 bfr = *(const bf16x8*)&Bs[cur][nt*16 + lr][kk*32 + ls*8];
                #pragma unroll
                for (int mt = 0; mt < MT; ++mt)
                    acc[mt][nt] = __builtin_amdgcn_mfma_f32_16x16x32_bf16(afr[mt], bfr, acc[mt][nt], 0, 0, 0);
            }
        }
        __syncthreads();
        cur ^= 1;
    }

    const int colb = blockIdx.x * BN + lr;
    const int rowb = blockIdx.y * BMt + w*16*MT + ls*4;
    #pragma unroll
    for (int mt = 0; mt < MT; ++mt)
    #pragma unroll
    for (int nt = 0; nt < 11; ++nt)
    #pragma unroll
    for (int q2 = 0; q2 < 4; ++q2) {
        int row = rowb + mt*16 + q2;
        int col = colb + nt*16;
        if (row >= Mreal) continue;
        float v = acc[mt][nt][q2];
        if constexpr (EPI == 0) {
            if (col < Nreal) outB[(size_t)row*ldo + col] = (bf16)(v + bias[col]);
        } else if constexpr (EPI == 2) {
            if (col < Nreal) {
                float sz = (col < 172) ? aux0[(size_t)row*172 + col]
                                       : ((col < 344) ? 0.f : aux1[col - 344]);
                outF[(size_t)row*ldo + col] = v + bias[col] + sz;
            }
        } else if constexpr (EPI == 3) {
            float vv = (col < Nreal) ? fmaxf(v + bias[col], 0.f) : 0.f;
            outB[(size_t)row*ldo + col] = (bf16)vv;
        } else {
            if (col < Nreal) outF[(size_t)row*ldo + col] = v + bias[col];
        }
    }
}

// ---------------- combined WQK/WVF GEMMs (KP=320, bf16 plain out), blockIdx.z selects ----------------
__global__ __launch_bounds__(256, 2)
void gemm_multi_kernel(const bf16* __restrict__ WKH, const bf16* __restrict__ WQHT,
                       const bf16* __restrict__ FCWT, const bf16* __restrict__ WVH,
                       bf16* __restrict__ WQKT, bf16* __restrict__ WVFT) {
    constexpr int KP = 320, NT = KP / BK;
    const int z = blockIdx.z, h = z & 1;
    const bf16 *A, *Bt; bf16* outB; int lda, ldo, Mreal, Nreal;
    if (z < 2) {
        if (blockIdx.x >= 2) return;
        A = WKH + (size_t)h*576*320;  lda = 320;
        Bt = WQHT + (size_t)h*352*320;
        outB = WQKT + (size_t)h*576*192; ldo = 192; Mreal = 576; Nreal = 192;
    } else {
        A = FCWT + (size_t)h*258;     lda = 576;
        Bt = WVH + (size_t)h*704*320;
        outB = WVFT + (size_t)h*576;  ldo = 1152; Mreal = 516; Nreal = 576;
    }
    __shared__ __align__(16) bf16 As[2][128][BK];
    __shared__ __align__(16) bf16 Bs[2][BN][BK];
    const int tid = threadIdx.x, w = tid >> 6, lane = tid & 63;
    const int lr = lane & 15, ls = lane >> 4;
    const int lrow = lane >> 3, lcol = (lane & 7) * 8;
    const bf16* aBase = A  + (size_t)(blockIdx.y * 128 + w * 32 + lrow) * lda + lcol;
    const bf16* bBase = Bt + (size_t)(blockIdx.x * BN + lrow) * KP + lcol;
    auto stage = [&](int buf, int k0) {
        #pragma unroll
        for (int i = 0; i < 4; ++i)
            gload16(aBase + (size_t)(i * 8) * lda + k0, &As[buf][w * 32 + i * 8][0]);
        #pragma unroll
        for (int jj = 0; jj < 6; ++jj) {
            int j = jj * 4 + w;
            if (j < 22) gload16(bBase + (size_t)(j * 8) * KP + k0, &Bs[buf][j * 8][0]);
        }
    };
    f32x4 acc[2][11];
    #pragma unroll
    for (int a = 0; a < 2; ++a)
        #pragma unroll
        for (int b2 = 0; b2 < 11; ++b2) acc[a][b2] = (f32x4)(0.0f);
    stage(0, 0);
    __syncthreads();
    int cur = 0;
    for (int t = 0; t < NT; ++t) {
        if (t + 1 < NT) stage(cur ^ 1, (t + 1) * BK);
        #pragma unroll
        for (int kk = 0; kk < 2; ++kk) {
            bf16x8 a0 = *(const bf16x8*)&As[cur][w*32 +      lr][kk*32 + ls*8];
            bf16x8 a1 = *(const bf16x8*)&As[cur][w*32 + 16 + lr][kk*32 + ls*8];
            #pragma unroll
            for (int nt = 0; nt < 11; ++nt) {
                bf16x8 bfr = *(const bf16x8*)&Bs[cur][nt*16 + lr][kk*32 + ls*8];
                acc[0][nt] = __builtin_amdgcn_mfma_f32_16x16x32_bf16(a0, bfr, acc[0][nt], 0, 0, 0);
                acc[1][nt] = __builtin_amdgcn_mfma_f32_16x16x32_bf16(a1, bfr, acc[1][nt], 0, 0, 0);
            }
        }
        __syncthreads();
        cur ^= 1;
    }
    const int colb = blockIdx.x * BN + lr;
    const int rowb = blockIdx.y * 128 + w*32 + ls*4;
    #pragma unroll
    for (int mt = 0; mt < 2; ++mt)
    #pragma unroll
    for (int nt = 0; nt < 11; ++nt)
    #pragma unroll
    for (int q2 = 0; q2 < 4; ++q2) {
        int row = rowb + mt*16 + q2;
        int col = colb + nt*16;
        if (row < Mreal && col < Nreal)
            outB[(size_t)row*ldo + col] = (bf16)acc[mt][nt][q2];
    }
}

// ---------------- attention-lite v8: QK preloaded to LDS (measured 104 us) ----------------
__global__ __launch_bounds__(256, 3)
void attn_lite_kernel(const bf16* __restrict__ QK, const bf16* __restrict__ nh16,
                      const float* __restrict__ edge_feat, const float* __restrict__ edge_t,
                      const int* __restrict__ nbr_idx, const float* __restrict__ freq,
                      const float* __restrict__ ph, const float* __restrict__ tnow,
                      bf16* __restrict__ ZB) {
    __shared__ __align__(16) bf16 zs[40 * 576];    // XOR-swizzled rows (pitch 1152 B)
    __shared__ __align__(16) bf16 qks[4 * 576];    // XOR-swizzled rows
    __shared__ __align__(16) float G[40][4];
    __shared__ float sfreq[172], sph[172];
    __shared__ float sdt[40];
    __shared__ int   ssrc[40];
    __shared__ float pp[2][20];

    const int r  = blockIdx.x;
    const int iA = 2 * r;
    const int t  = threadIdx.x;
    const int w  = t >> 6, lane = t & 63;
    const int lr = lane & 15, ls = lane >> 4;

    auto zsa = [&](int row, int c) -> bf16* {
        unsigned b = (unsigned)(row * 1152 + c * 2) ^ (unsigned)((row & 7) << 4);
        return (bf16*)((char*)zs + b);
    };
    auto qka = [&](int row, int c) -> bf16* {
        unsigned b = (unsigned)(row * 1152 + c * 2) ^ (unsigned)((row & 3) << 5);
        return (bf16*)((char*)qks + b);
    };

    // QK preload into LDS (latency hides under z-build)
    #pragma unroll
    for (int s = 0; s < 2; ++s) {
        int idx = t + s * 256;
        if (idx < 288) {
            int m = idx / 72, g = idx % 72;
            *(bf16x8*)qka(m, g * 8) =
                *(const bf16x8*)(QK + (size_t)(iA + (m >> 1)) * 1152 + (m & 1) * 576 + g * 8);
        }
    }

    // Phase A: issue ef loads into static register slots (issue-early)
    f32x4 efA[4], efB[4];
    #pragma unroll
    for (int s = 0; s < 4; ++s) {
        int idx = t + (s + 3) * 256;
        if (idx >= 880 && idx < 1720) {
            int i2 = idx - 880;
            int row = i2 / 21, c = 22 + i2 % 21;
            const float* ep = edge_feat + (size_t)(iA * 20 + row) * 172 + (c * 8 - 172);
            efA[s] = *(const f32x4*)ep;
            efB[s] = *(const f32x4*)(ep + 4);
        }
    }

    if (t < 172) { sfreq[t] = freq[t]; sph[t] = ph[t]; }
    if (t >= 192 && t < 232) {
        int e2 = t - 192, ge = iA * 20 + e2;
        sdt[e2]  = tnow[0] - edge_t[ge];
        ssrc[e2] = nbr_idx[ge];
    }
    __syncthreads();

    // Phase B: nh segment + tenc/zero segments
    #pragma unroll
    for (int it = 0; it < 4; ++it) {
        int idx = t + it * 256;
        if (idx < 880) {
            int row = idx / 22, c = idx % 22;
            bf16x8 v;
            if (c < 21) {
                v = *(const bf16x8*)(nh16 + (size_t)ssrc[row] * 192 + c * 8);
            } else {
                int ge = iA * 20 + row;
                #pragma unroll
                for (int e = 0; e < 8; ++e) {
                    int k = 168 + e;
                    v[e] = (k < 172) ? nh16[(size_t)ssrc[row] * 192 + k]
                                     : (bf16)edge_feat[(size_t)ge * 172 + (k - 172)];
                }
            }
            *(bf16x8*)zsa(row, c * 8) = v;
        }
    }
    #pragma unroll
    for (int it = 6; it < 12; ++it) {
        int idx = t + it * 256;
        if (idx >= 1720 && idx < 2880) {
            int row, c;
            bf16x8 v;
            if (idx < 2600) {
                int i3 = idx - 1720;
                row = i3 / 22; c = 43 + i3 % 22;
                float dt = sdt[row];
                int k0 = c * 8;
                #pragma unroll
                for (int e = 0; e < 8; ++e) {
                    int k = k0 + e;
                    v[e] = (k < 516) ? (bf16)__cosf(dt * sfreq[k - 344] + sph[k - 344]) : (bf16)0.f;
                }
            } else {
                int i4 = idx - 2600;
                row = i4 / 7; c = 65 + i4 % 7;
                #pragma unroll
                for (int e = 0; e < 8; ++e) v[e] = (bf16)0.f;
            }
            *(bf16x8*)zsa(row, c * 8) = v;
        }
    }
    // Phase C: drain ef regs -> zs
    #pragma unroll
    for (int s = 0; s < 4; ++s) {
        int idx = t + (s + 3) * 256;
        if (idx >= 880 && idx < 1720) {
            int i2 = idx - 880;
            int row = i2 / 21, c = 22 + i2 % 21;
            bf16x8 v;
            #pragma unroll
            for (int e = 0; e < 4; ++e) { v[e] = (bf16)efA[s][e]; v[e+4] = (bf16)efB[s][e]; }
            *(bf16x8*)zsa(row, c * 8) = v;
        }
    }
    __syncthreads();

    // MFMA logits: G[4 x 40] = qks(4x576) . zs^T ; waves 0..2, A from LDS
    if (w < 3) {
        int brow = w * 16 + lr; if (brow > 39) brow = 39;
        f32x4 acc = (f32x4)(0.0f);
        __builtin_amdgcn_s_setprio(1);
        #pragma unroll
        for (int ks = 0; ks < 18; ++ks) {
            bf16x8 af = *(const bf16x8*)qka(lr & 3, ks * 32 + ls * 8);
            bf16x8 bf = *(const bf16x8*)zsa(brow, ks * 32 + ls * 8);
            acc = __builtin_amdgcn_mfma_f32_16x16x32_bf16(af, bf, acc, 0, 0, 0);
        }
        __builtin_amdgcn_s_setprio(0);
        int col = w * 16 + lr;
        if (ls == 0 && col < 40) *(f32x4*)&G[col][0] = acc;
    }
    __syncthreads();

    // wave-parallel softmax: wave 0, lane = h*32 + knbr
    if (t < 64) {
        int h = lane >> 5, knbr = lane & 31;
        bool act = knbr < 20;
        float l = -1e30f;
        if (act) {
            int z0 = (knbr / 10) * 20 + 2 * (knbr % 10);
            l = (G[z0][h] + G[z0 + 1][2 + h]) * 0.0622573006f;   // 1/sqrt(258)
        }
        float m = l;
        #pragma unroll
        for (int o = 16; o >= 1; o >>= 1) m = fmaxf(m, __shfl_xor(m, o));
        float e = act ? __expf(l - m) : 0.f;
        float s2 = e;
        #pragma unroll
        for (int o = 16; o >= 1; o >>= 1) s2 += __shfl_xor(s2, o);
        if (act) pp[h][knbr] = e / s2;
    }
    __syncthreads();

    // ZB: 288 tasks (nsel, 4-elem chunk); z read ONCE, both heads accumulated
    #pragma unroll
    for (int it = 0; it < 2; ++it) {
        int idx = t + it * 256;
        if (idx < 288) {
            int nsel = idx / 144, c4 = (idx % 144) * 4;
            float a0[4] = {0.f, 0.f, 0.f, 0.f};
            float a1[4] = {0.f, 0.f, 0.f, 0.f};
            #pragma unroll
            for (int knbr = 0; knbr < 20; ++knbr) {
                int z0 = (knbr / 10) * 20 + 2 * (knbr % 10) + nsel;
                bf16x4 zv = *(const bf16x4*)zsa(z0, c4);
                float p0 = pp[0][knbr], p1 = pp[1][knbr];
                #pragma unroll
                for (int i = 0; i < 4; ++i) {
                    float zf = (float)zv[i];
                    a0[i] += p0 * zf;
                    a1[i] += p1 * zf;
                }
            }
            bf16x4 o0, o1;
            #pragma unroll
            for (int i = 0; i < 4; ++i) { o0[i] = (bf16)a0[i]; o1[i] = (bf16)a1[i]; }
            *(bf16x4*)(ZB + (size_t)(iA + nsel) * 1152 + c4)       = o0;   // head 0
            *(bf16x4*)(ZB + (size_t)(iA + nsel) * 1152 + 576 + c4) = o1;   // head 1
        }
    }
}

// ---------------- LayerNorm + build X = [h_ln, node_h, 0pad] ----------------
__global__ __launch_bounds__(256)
void ln_x_kernel(const float* __restrict__ fcr, const float* __restrict__ g,
                 const float* __restrict__ b, const bf16* __restrict__ nh16,
                 bf16* __restrict__ X) {
    __shared__ float red[2][4];
    __shared__ float mb[2];
    const size_t i = blockIdx.x;
    const int t = threadIdx.x;
    int c0 = t, c1 = t + 256, c2 = t + 512;
    float v0 = fcr[i*516 + c0];
    float v1 = (c1 < 516) ? fcr[i*516 + c1] : 0.f;
    float v2 = (c2 < 516) ? fcr[i*516 + c2] : 0.f;
    float s = v0 + v1 + v2, ss = v0*v0 + v1*v1 + v2*v2;
    #pragma unroll
    for (int o = 32; o; o >>= 1) { s += __shfl_down(s, o); ss += __shfl_down(ss, o); }
    if ((t & 63) == 0) { red[0][t >> 6] = s; red[1][t >> 6] = ss; }
    __syncthreads();
    if (t == 0) {
        float S  = red[0][0] + red[0][1] + red[0][2] + red[0][3];
        float SS = red[1][0] + red[1][1] + red[1][2] + red[1][3];
        float mean = S / 516.f;
        float var  = SS / 516.f - mean*mean;
        mb[0] = mean; mb[1] = rsqrtf(var + 1e-5f);
    }
    __syncthreads();
    float mean = mb[0], rstd = mb[1];
    X[i*704 + c0] = (bf16)((v0 - mean)*rstd*g[c0] + b[c0]);
    if (c1 < 516) X[i*704 + c1] = (bf16)((v1 - mean)*rstd*g[c1] + b[c1]);
    if (c2 < 516) X[i*704 + c2] = (bf16)((v2 - mean)*rstd*g[c2] + b[c2]);
    for (int c = 516 + t; c < 704; c += 256)
        X[i*704 + c] = (c < 688) ? nh16[i*192 + (c - 516)] : (bf16)0.f;
}

// ---------------- launch ----------------
extern "C" void kernel_launch(void* const* d_in, const int* in_sizes, int n_in,
                              void* d_out, int out_size, void* d_ws, size_t ws_size,
                              hipStream_t stream) {
    const float* node_h     = (const float*)d_in[0];
    const float* edge_t     = (const float*)d_in[1];
    const float* edge_feat  = (const float*)d_in[2];
    const int*   nbr_idx    = (const int*)d_in[3];
    const float* t_now      = (const float*)d_in[4];
    const float* w_q        = (const float*)d_in[6];
    const float* w_k        = (const float*)d_in[7];
    const float* w_v        = (const float*)d_in[8];
    const float* basis_freq = (const float*)d_in[9];
    const float* phase      = (const float*)d_in[10];
    const float* ln_g       = (const float*)d_in[11];
    const float* ln_b       = (const float*)d_in[12];
    const float* fc_w       = (const float*)d_in[13];
    const float* fc_b       = (const float*)d_in[14];
    const float* m1_w       = (const float*)d_in[15];
    const float* m1_b       = (const float*)d_in[16];
    const float* m2_w       = (const float*)d_in[17];
    const float* m2_b       = (const float*)d_in[18];

    char* ws = (char*)d_ws;
    bf16*  FCWT = (bf16*)(ws + FCWT_OFF);
    bf16*  M1WT = (bf16*)(ws + M1WT_OFF);
    bf16*  M2WT = (bf16*)(ws + M2WT_OFF);
    bf16*  WKH  = (bf16*)(ws + WKH_OFF);
    bf16*  WQHT = (bf16*)(ws + WQHT_OFF);
    bf16*  WVH  = (bf16*)(ws + WVH_OFF);
    bf16*  WQKT = (bf16*)(ws + WQKT_OFF);
    bf16*  WVFT = (bf16*)(ws + WVFT_OFF);
    float* QB   = (float*)(ws + QB_OFF);
    float* QKB  = (float*)(ws + QKB_OFF);
    float* CPH  = (float*)(ws + CPH_OFF);
    bf16*  NH16 = (bf16*)(ws + NH16_OFF);
    bf16*  QK   = (bf16*)(ws + QK_OFF);
    bf16*  ZB   = (bf16*)(ws + ZB_OFF);
    float* FCR  = (float*)(ws + FCR_OFF);
    bf16*  Xb   = (bf16*)(ws + X_OFF);
    bf16*  Rb   = (bf16*)(ws + R_OFF);

    hipMemsetAsync(ws, 0, NH16_OFF, stream);

    // all prep in one launch: y0-2 transpose-packs, y3 misc, y4 qbias
    prep_all_kernel<<<dim3(1024, 5), 256, 0, stream>>>(
        fc_w, m1_w, m2_w, w_k, w_q, w_v, node_h, phase,
        FCWT, M1WT, M2WT, WKH, WQHT, WVH, NH16, CPH, QB);
    qkb_kernel<<<1152, 256, 0, stream>>>(w_k, QB, QKB);

    // WQK^T (z=0,1) and WVF^T (z=2,3) in one launch
    gemm_multi_kernel<<<dim3(4, 5, 4), 256, 0, stream>>>(WKH, WQHT, FCWT, WVH, WQKT, WVFT);

    // qk = NH16 @ WQK^T + qkb   -> QK [NPAD][1152]   (BM=64, 2 blocks/CU)
    gemm_kernel<192, 0, 1><<<dim3(7, 158), 256, 0, stream>>>(
        NH16, 192, WQKT, nullptr, QK, 1152, QKB, nullptr, nullptr, NN, 1152);

    // attention -> ZB [NPAD][1152]
    attn_lite_kernel<<<NN / 2, 256, 0, stream>>>(
        QK, NH16, edge_feat, edge_t, nbr_idx, basis_freq, phase, t_now, ZB);

    // fcr = ZB @ WVF^T + fc_b + self_z   (BM=64)
    gemm_kernel<1152, 2, 1><<<dim3(3, 158), 256, 0, stream>>>(
        ZB, 1152, WVFT, FCR, nullptr, 516, fc_b, node_h, CPH, NN, 516);

    ln_x_kernel<<<NN, 256, 0, stream>>>(FCR, ln_g, ln_b, NH16, Xb);

    // m1 + relu  (BM=64; cols 172..175 zeroed so m2 A-loads are clean)
    gemm_kernel<704, 3, 1><<<dim3(1, 158), 256, 0, stream>>>(
        Xb, 704, M1WT, nullptr, Rb, 192, m1_b, nullptr, nullptr, NN, 172);

    // m2 -> out  (BM=64; K-pad rows of M2WT are zero so poison A cols are inert)
    gemm_kernel<192, 4, 1><<<dim3(1, 158), 256, 0, stream>>>(
        Rb, 192, M2WT, (float*)d_out, nullptr, 172, m2_b, nullptr, nullptr, NN, 172);
}

// Round 17
// 231.078 us; speedup vs baseline: 1.2415x; 1.0151x over previous
//
#include <hip/hip_runtime.h>
#include <hip/hip_bf16.h>
#include <math.h>

typedef __bf16 bf16;
typedef __attribute__((ext_vector_type(4))) __bf16 bf16x4;
typedef __attribute__((ext_vector_type(8))) __bf16 bf16x8;
typedef __attribute__((ext_vector_type(4))) float f32x4;

// ---------------- problem constants ----------------
constexpr int NN   = 10000;
constexpr int NPAD = 10112;            // 128-aligned (DMA overrun pad)
constexpr int BN = 176, BK = 64;

// ---------------- workspace layout (bytes) ----------------
constexpr size_t FCWT_OFF = 0;                         // bf16 [528][576]   fcw^T (zero-padded)
constexpr size_t M1WT_OFF = 608256;                    // bf16 [176][704]
constexpr size_t M2WT_OFF = 856064;                    // bf16 [176][192]
constexpr size_t WKH_OFF  = 923648;                    // bf16 [2*576][320] wk head-slices
constexpr size_t WQHT_OFF = 1660928;                   // bf16 [2*352][320] wq head-slices (rows<172)
constexpr size_t WVH_OFF  = 2111488;                   // bf16 [2*704][320] wv head-slices
constexpr size_t WQKT_OFF = 3012608;                   // bf16 [1232][192]  WQK^T (qk GEMM B)
constexpr size_t WVFT_OFF = 3485696;                   // bf16 [528][1152]  WVF^T (fusedFC B)
constexpr size_t QB_OFF   = 4702208;                   // f32 [516]
constexpr size_t QKB_OFF  = 4706304;                   // f32 [1232]
constexpr size_t CPH_OFF  = 4714496;                   // f32 [172]
constexpr size_t NH16_OFF = 4715520;                   // bf16 [NPAD][192]
constexpr size_t QK_OFF   = NH16_OFF + (size_t)NPAD*192*2;    // bf16 [NPAD][1152]
constexpr size_t ZB_OFF   = QK_OFF   + (size_t)NPAD*1152*2;   // bf16 [NPAD][1152]
constexpr size_t FCR_OFF  = ZB_OFF   + (size_t)NPAD*1152*2;   // f32 [NN][516]
constexpr size_t X_OFF    = FCR_OFF  + (size_t)NN*516*4;      // bf16 [NPAD][704]
constexpr size_t R_OFF    = X_OFF    + (size_t)NPAD*704*2;    // bf16 [NPAD][192]

// ---------------- global_load_lds helper (width 16) ----------------
typedef __attribute__((address_space(3))) void lds_void;
typedef const __attribute__((address_space(1))) void glb_void;
__device__ __forceinline__ void gload16(const void* g, void* l) {
    __builtin_amdgcn_global_load_lds((glb_void*)(uintptr_t)g,
                                     (lds_void*)(unsigned int)(uintptr_t)l, 16, 0, 0);
}

// ---------------- fused prep: transpose-packs + misc packs + qbias ----------------
__global__ __launch_bounds__(256)
void prep_all_kernel(const float* __restrict__ fcw, const float* __restrict__ m1w,
                     const float* __restrict__ m2w, const float* __restrict__ wk,
                     const float* __restrict__ wq, const float* __restrict__ wv,
                     const float* __restrict__ node_h, const float* __restrict__ phase,
                     bf16* __restrict__ FCWT, bf16* __restrict__ M1WT, bf16* __restrict__ M2WT,
                     bf16* __restrict__ WKH, bf16* __restrict__ WQHT, bf16* __restrict__ WVH,
                     bf16* __restrict__ nh16, float* __restrict__ cph, float* __restrict__ QB) {
    const int y = blockIdx.y;
    if (y < 3) {
        __shared__ float tile[32][33];
        const float* src; bf16* dst; int K, C, LD;
        switch (y) {
            case 0:  src = fcw; K = 516; C = 516; dst = FCWT; LD = 576; break;
            case 1:  src = m1w; K = 688; C = 172; dst = M1WT; LD = 704; break;
            default: src = m2w; K = 172; C = 172; dst = M2WT; LD = 192; break;
        }
        const int tilesC = (C + 31) >> 5, tilesK = (K + 31) >> 5;
        const int nt = tilesC * tilesK;
        const int tx = threadIdx.x & 31, ty = threadIdx.x >> 5;
        for (int tb = blockIdx.x; tb < nt; tb += gridDim.x) {
            int tc = tb % tilesC, tk = tb / tilesC;
            #pragma unroll
            for (int i = 0; i < 4; ++i) {
                int k = tk*32 + ty + i*8, c = tc*32 + tx;
                tile[ty + i*8][tx] = (k < K && c < C) ? src[(size_t)k*C + c] : 0.f;
            }
            __syncthreads();
            #pragma unroll
            for (int i = 0; i < 4; ++i) {
                int c = tc*32 + ty + i*8, k = tk*32 + tx;
                if (c < C && k < K) dst[(size_t)c*LD + k] = (bf16)tile[tx][ty + i*8];
            }
            __syncthreads();
        }
    } else if (y == 3) {
        constexpr int T0 = 2*516*258;
        constexpr int T1 = T0 + 2*172*258;
        constexpr int T2 = T1 + 2*516*258;
        constexpr int T3 = T2 + NN*192;
        constexpr int T4 = T3 + 172;
        for (int idx = blockIdx.x * blockDim.x + threadIdx.x; idx < T4;
             idx += gridDim.x * blockDim.x) {
            if (idx < T0) {
                int h = idx / (516*258), rem = idx % (516*258), d = rem / 258, j = rem % 258;
                WKH[((size_t)h*576 + d)*320 + j] = (bf16)wk[(size_t)d*516 + h*258 + j];
            } else if (idx < T1) {
                int i = idx - T0;
                int h = i / (172*258), rem = i % (172*258), k = rem / 258, j = rem % 258;
                WQHT[((size_t)h*352 + k)*320 + j] = (bf16)wq[(size_t)k*516 + h*258 + j];
            } else if (idx < T2) {
                int i = idx - T1;
                int h = i / (516*258), rem = i % (516*258), c = rem / 258, j = rem % 258;
                WVH[((size_t)h*704 + c)*320 + j] = (bf16)wv[(size_t)c*516 + h*258 + j];
            } else if (idx < T3) {
                int i = idx - T2, r = i / 192, c = i % 192;
                nh16[i] = (c < 172) ? (bf16)node_h[(size_t)r*172 + c] : (bf16)0.f;
            } else cph[idx - T3] = cosf(phase[idx - T3]);
        }
    } else {
        if (blockIdx.x >= 516) return;
        __shared__ float red[256];
        const int c = blockIdx.x, j = threadIdx.x;
        red[j] = (j < 172) ? cosf(phase[j]) * wq[(size_t)(344 + j) * 516 + c] : 0.f;
        __syncthreads();
        #pragma unroll
        for (int o = 128; o; o >>= 1) { if (j < o) red[j] += red[j + o]; __syncthreads(); }
        if (j == 0) QB[c] = red[0];
    }
}

// qkb[h*576+d] = sum_{j<258} QB[h*258+j] * wk[d][h*258+j]   (d<516, else 0)
__global__ __launch_bounds__(256)
void qkb_kernel(const float* __restrict__ wk, const float* __restrict__ QB,
                float* __restrict__ qkb) {
    __shared__ float red[256];
    const int hd = blockIdx.x, h = hd / 576, d = hd % 576, t = threadIdx.x;
    float a = 0.f;
    if (d < 516) {
        a = QB[h*258 + t] * wk[(size_t)d*516 + h*258 + t];
        if (t < 2) a += QB[h*258 + 256 + t] * wk[(size_t)d*516 + h*258 + 256 + t];
    }
    red[t] = a; __syncthreads();
    #pragma unroll
    for (int o = 128; o; o >>= 1) { if (t < o) red[t] += red[t + o]; __syncthreads(); }
    if (t == 0) qkb[hd] = red[0];
}

// ---------------- MFMA GEMM (DMA staging + 2-phase dbuf), MT row-tiles/wave ----------------
template<int KP, int EPI, int MT>
__global__ __launch_bounds__(256, 2)
void gemm_kernel(const bf16* __restrict__ A, int lda, const bf16* __restrict__ Bt,
                 float* __restrict__ outF, bf16* __restrict__ outB, int ldo,
                 const float* __restrict__ bias,
                 const float* __restrict__ aux0, const float* __restrict__ aux1,
                 int Mreal, int Nreal) {
    constexpr int NT  = KP / BK;
    constexpr int BMt = 64 * MT;
    __shared__ __align__(16) bf16 As[2][BMt][BK];
    __shared__ __align__(16) bf16 Bs[2][BN][BK];

    const int tid  = threadIdx.x;
    const int w    = tid >> 6;
    const int lane = tid & 63;
    const int lr   = lane & 15;
    const int ls   = lane >> 4;
    const int lrow = lane >> 3;
    const int lcol = (lane & 7) * 8;

    const bf16* aBase = A  + (size_t)(blockIdx.y * BMt + w * 16 * MT + lrow) * lda + lcol;
    const bf16* bBase = Bt + (size_t)(blockIdx.x * BN + lrow) * KP + lcol;

    auto stage = [&](int buf, int k0) {
        #pragma unroll
        for (int i = 0; i < 2 * MT; ++i)
            gload16(aBase + (size_t)(i * 8) * lda + k0, &As[buf][w * 16 * MT + i * 8][0]);
        #pragma unroll
        for (int jj = 0; jj < 6; ++jj) {
            int j = jj * 4 + w;
            if (j < 22) gload16(bBase + (size_t)(j * 8) * KP + k0, &Bs[buf][j * 8][0]);
        }
    };

    f32x4 acc[MT][11];
    #pragma unroll
    for (int a = 0; a < MT; ++a)
        #pragma unroll
        for (int b2 = 0; b2 < 11; ++b2) acc[a][b2] = (f32x4)(0.0f);

    stage(0, 0);
    __syncthreads();
    int cur = 0;
    for (int t = 0; t < NT; ++t) {
        if (t + 1 < NT) stage(cur ^ 1, (t + 1) * BK);
        #pragma unroll
        for (int kk = 0; kk < 2; ++kk) {
            bf16x8 afr[MT];
            #pragma unroll
            for (int mt = 0; mt < MT; ++mt)
                afr[mt] = *(const bf16x8*)&As[cur][w*16*MT + mt*16 + lr][kk*32 + ls*8];
            #pragma unroll
            for (int nt = 0; nt < 11; ++nt) {
                bf16x8 bfr = *(const bf16x8*)&Bs[cur][nt*16 + lr][kk*32 + ls*8];
                #pragma unroll
                for (int mt = 0; mt < MT; ++mt)
                    acc[mt][nt] = __builtin_amdgcn_mfma_f32_16x16x32_bf16(afr[mt], bfr, acc[mt][nt], 0, 0, 0);
            }
        }
        __syncthreads();
        cur ^= 1;
    }

    const int colb = blockIdx.x * BN + lr;
    const int rowb = blockIdx.y * BMt + w*16*MT + ls*4;
    #pragma unroll
    for (int mt = 0; mt < MT; ++mt)
    #pragma unroll
    for (int nt = 0; nt < 11; ++nt)
    #pragma unroll
    for (int q2 = 0; q2 < 4; ++q2) {
        int row = rowb + mt*16 + q2;
        int col = colb + nt*16;
        if (row >= Mreal) continue;
        float v = acc[mt][nt][q2];
        if constexpr (EPI == 0) {
            if (col < Nreal) outB[(size_t)row*ldo + col] = (bf16)(v + bias[col]);
        } else if constexpr (EPI == 2) {
            if (col < Nreal) {
                float sz = (col < 172) ? aux0[(size_t)row*172 + col]
                                       : ((col < 344) ? 0.f : aux1[col - 344]);
                outF[(size_t)row*ldo + col] = v + bias[col] + sz;
            }
        } else if constexpr (EPI == 3) {
            float vv = (col < Nreal) ? fmaxf(v + bias[col], 0.f) : 0.f;
            outB[(size_t)row*ldo + col] = (bf16)vv;
        } else {
            if (col < Nreal) outF[(size_t)row*ldo + col] = v + bias[col];
        }
    }
}

// ---------------- combined WQK/WVF GEMMs (KP=320, bf16 plain out), blockIdx.z selects ----------------
__global__ __launch_bounds__(256, 2)
void gemm_multi_kernel(const bf16* __restrict__ WKH, const bf16* __restrict__ WQHT,
                       const bf16* __restrict__ FCWT, const bf16* __restrict__ WVH,
                       bf16* __restrict__ WQKT, bf16* __restrict__ WVFT) {
    constexpr int KP = 320, NT = KP / BK;
    const int z = blockIdx.z, h = z & 1;
    const bf16 *A, *Bt; bf16* outB; int lda, ldo, Mreal, Nreal;
    if (z < 2) {
        if (blockIdx.x >= 2) return;
        A = WKH + (size_t)h*576*320;  lda = 320;
        Bt = WQHT + (size_t)h*352*320;
        outB = WQKT + (size_t)h*576*192; ldo = 192; Mreal = 576; Nreal = 192;
    } else {
        A = FCWT + (size_t)h*258;     lda = 576;
        Bt = WVH + (size_t)h*704*320;
        outB = WVFT + (size_t)h*576;  ldo = 1152; Mreal = 516; Nreal = 576;
    }
    __shared__ __align__(16) bf16 As[2][128][BK];
    __shared__ __align__(16) bf16 Bs[2][BN][BK];
    const int tid = threadIdx.x, w = tid >> 6, lane = tid & 63;
    const int lr = lane & 15, ls = lane >> 4;
    const int lrow = lane >> 3, lcol = (lane & 7) * 8;
    const bf16* aBase = A  + (size_t)(blockIdx.y * 128 + w * 32 + lrow) * lda + lcol;
    const bf16* bBase = Bt + (size_t)(blockIdx.x * BN + lrow) * KP + lcol;
    auto stage = [&](int buf, int k0) {
        #pragma unroll
        for (int i = 0; i < 4; ++i)
            gload16(aBase + (size_t)(i * 8) * lda + k0, &As[buf][w * 32 + i * 8][0]);
        #pragma unroll
        for (int jj = 0; jj < 6; ++jj) {
            int j = jj * 4 + w;
            if (j < 22) gload16(bBase + (size_t)(j * 8) * KP + k0, &Bs[buf][j * 8][0]);
        }
    };
    f32x4 acc[2][11];
    #pragma unroll
    for (int a = 0; a < 2; ++a)
        #pragma unroll
        for (int b2 = 0; b2 < 11; ++b2) acc[a][b2] = (f32x4)(0.0f);
    stage(0, 0);
    __syncthreads();
    int cur = 0;
    for (int t = 0; t < NT; ++t) {
        if (t + 1 < NT) stage(cur ^ 1, (t + 1) * BK);
        #pragma unroll
        for (int kk = 0; kk < 2; ++kk) {
            bf16x8 a0 = *(const bf16x8*)&As[cur][w*32 +      lr][kk*32 + ls*8];
            bf16x8 a1 = *(const bf16x8*)&As[cur][w*32 + 16 + lr][kk*32 + ls*8];
            #pragma unroll
            for (int nt = 0; nt < 11; ++nt) {
                bf16x8 bfr = *(const bf16x8*)&Bs[cur][nt*16 + lr][kk*32 + ls*8];
                acc[0][nt] = __builtin_amdgcn_mfma_f32_16x16x32_bf16(a0, bfr, acc[0][nt], 0, 0, 0);
                acc[1][nt] = __builtin_amdgcn_mfma_f32_16x16x32_bf16(a1, bfr, acc[1][nt], 0, 0, 0);
            }
        }
        __syncthreads();
        cur ^= 1;
    }
    const int colb = blockIdx.x * BN + lr;
    const int rowb = blockIdx.y * 128 + w*32 + ls*4;
    #pragma unroll
    for (int mt = 0; mt < 2; ++mt)
    #pragma unroll
    for (int nt = 0; nt < 11; ++nt)
    #pragma unroll
    for (int q2 = 0; q2 < 4; ++q2) {
        int row = rowb + mt*16 + q2;
        int col = colb + nt*16;
        if (row < Mreal && col < Nreal)
            outB[(size_t)row*ldo + col] = (bf16)acc[mt][nt][q2];
    }
}

// ---------------- attention-lite v8: QK preloaded to LDS (measured ~104 us) ----------------
__global__ __launch_bounds__(256, 3)
void attn_lite_kernel(const bf16* __restrict__ QK, const bf16* __restrict__ nh16,
                      const float* __restrict__ edge_feat, const float* __restrict__ edge_t,
                      const int* __restrict__ nbr_idx, const float* __restrict__ freq,
                      const float* __restrict__ ph, const float* __restrict__ tnow,
                      bf16* __restrict__ ZB) {
    __shared__ __align__(16) bf16 zs[40 * 576];    // XOR-swizzled rows (pitch 1152 B)
    __shared__ __align__(16) bf16 qks[4 * 576];    // XOR-swizzled rows
    __shared__ __align__(16) float G[40][4];
    __shared__ float sfreq[172], sph[172];
    __shared__ float sdt[40];
    __shared__ int   ssrc[40];
    __shared__ float pp[2][20];

    const int r  = blockIdx.x;
    const int iA = 2 * r;
    const int t  = threadIdx.x;
    const int w  = t >> 6, lane = t & 63;
    const int lr = lane & 15, ls = lane >> 4;

    auto zsa = [&](int row, int c) -> bf16* {
        unsigned b = (unsigned)(row * 1152 + c * 2) ^ (unsigned)((row & 7) << 4);
        return (bf16*)((char*)zs + b);
    };
    auto qka = [&](int row, int c) -> bf16* {
        unsigned b = (unsigned)(row * 1152 + c * 2) ^ (unsigned)((row & 3) << 5);
        return (bf16*)((char*)qks + b);
    };

    // QK preload into LDS (latency hides under z-build)
    #pragma unroll
    for (int s = 0; s < 2; ++s) {
        int idx = t + s * 256;
        if (idx < 288) {
            int m = idx / 72, g = idx % 72;
            *(bf16x8*)qka(m, g * 8) =
                *(const bf16x8*)(QK + (size_t)(iA + (m >> 1)) * 1152 + (m & 1) * 576 + g * 8);
        }
    }

    // Phase A: issue ef loads into static register slots (issue-early)
    f32x4 efA[4], efB[4];
    #pragma unroll
    for (int s = 0; s < 4; ++s) {
        int idx = t + (s + 3) * 256;
        if (idx >= 880 && idx < 1720) {
            int i2 = idx - 880;
            int row = i2 / 21, c = 22 + i2 % 21;
            const float* ep = edge_feat + (size_t)(iA * 20 + row) * 172 + (c * 8 - 172);
            efA[s] = *(const f32x4*)ep;
            efB[s] = *(const f32x4*)(ep + 4);
        }
    }

    if (t < 172) { sfreq[t] = freq[t]; sph[t] = ph[t]; }
    if (t >= 192 && t < 232) {
        int e2 = t - 192, ge = iA * 20 + e2;
        sdt[e2]  = tnow[0] - edge_t[ge];
        ssrc[e2] = nbr_idx[ge];
    }
    __syncthreads();

    // Phase B: nh segment + tenc/zero segments
    #pragma unroll
    for (int it = 0; it < 4; ++it) {
        int idx = t + it * 256;
        if (idx < 880) {
            int row = idx / 22, c = idx % 22;
            bf16x8 v;
            if (c < 21) {
                v = *(const bf16x8*)(nh16 + (size_t)ssrc[row] * 192 + c * 8);
            } else {
                int ge = iA * 20 + row;
                #pragma unroll
                for (int e = 0; e < 8; ++e) {
                    int k = 168 + e;
                    v[e] = (k < 172) ? nh16[(size_t)ssrc[row] * 192 + k]
                                     : (bf16)edge_feat[(size_t)ge * 172 + (k - 172)];
                }
            }
            *(bf16x8*)zsa(row, c * 8) = v;
        }
    }
    #pragma unroll
    for (int it = 6; it < 12; ++it) {
        int idx = t + it * 256;
        if (idx >= 1720 && idx < 2880) {
            int row, c;
            bf16x8 v;
            if (idx < 2600) {
                int i3 = idx - 1720;
                row = i3 / 22; c = 43 + i3 % 22;
                float dt = sdt[row];
                int k0 = c * 8;
                #pragma unroll
                for (int e = 0; e < 8; ++e) {
                    int k = k0 + e;
                    v[e] = (k < 516) ? (bf16)__cosf(dt * sfreq[k - 344] + sph[k - 344]) : (bf16)0.f;
                }
            } else {
                int i4 = idx - 2600;
                row = i4 / 7; c = 65 + i4 % 7;
                #pragma unroll
                for (int e = 0; e < 8; ++e) v[e] = (bf16)0.f;
            }
            *(bf16x8*)zsa(row, c * 8) = v;
        }
    }
    // Phase C: drain ef regs -> zs
    #pragma unroll
    for (int s = 0; s < 4; ++s) {
        int idx = t + (s + 3) * 256;
        if (idx >= 880 && idx < 1720) {
            int i2 = idx - 880;
            int row = i2 / 21, c = 22 + i2 % 21;
            bf16x8 v;
            #pragma unroll
            for (int e = 0; e < 4; ++e) { v[e] = (bf16)efA[s][e]; v[e+4] = (bf16)efB[s][e]; }
            *(bf16x8*)zsa(row, c * 8) = v;
        }
    }
    __syncthreads();

    // MFMA logits: G[4 x 40] = qks(4x576) . zs^T ; waves 0..2, A from LDS
    if (w < 3) {
        int brow = w * 16 + lr; if (brow > 39) brow = 39;
        f32x4 acc = (f32x4)(0.0f);
        __builtin_amdgcn_s_setprio(1);
        #pragma unroll
        for (int ks = 0; ks < 18; ++ks) {
            bf16x8 af = *(const bf16x8*)qka(lr & 3, ks * 32 + ls * 8);
            bf16x8 bf = *(const bf16x8*)zsa(brow, ks * 32 + ls * 8);
            acc = __builtin_amdgcn_mfma_f32_16x16x32_bf16(af, bf, acc, 0, 0, 0);
        }
        __builtin_amdgcn_s_setprio(0);
        int col = w * 16 + lr;
        if (ls == 0 && col < 40) *(f32x4*)&G[col][0] = acc;
    }
    __syncthreads();

    // wave-parallel softmax: wave 0, lane = h*32 + knbr
    if (t < 64) {
        int h = lane >> 5, knbr = lane & 31;
        bool act = knbr < 20;
        float l = -1e30f;
        if (act) {
            int z0 = (knbr / 10) * 20 + 2 * (knbr % 10);
            l = (G[z0][h] + G[z0 + 1][2 + h]) * 0.0622573006f;   // 1/sqrt(258)
        }
        float m = l;
        #pragma unroll
        for (int o = 16; o >= 1; o >>= 1) m = fmaxf(m, __shfl_xor(m, o));
        float e = act ? __expf(l - m) : 0.f;
        float s2 = e;
        #pragma unroll
        for (int o = 16; o >= 1; o >>= 1) s2 += __shfl_xor(s2, o);
        if (act) pp[h][knbr] = e / s2;
    }
    __syncthreads();

    // ZB: 288 tasks (nsel, 4-elem chunk); z read ONCE, both heads accumulated
    #pragma unroll
    for (int it = 0; it < 2; ++it) {
        int idx = t + it * 256;
        if (idx < 288) {
            int nsel = idx / 144, c4 = (idx % 144) * 4;
            float a0[4] = {0.f, 0.f, 0.f, 0.f};
            float a1[4] = {0.f, 0.f, 0.f, 0.f};
            #pragma unroll
            for (int knbr = 0; knbr < 20; ++knbr) {
                int z0 = (knbr / 10) * 20 + 2 * (knbr % 10) + nsel;
                bf16x4 zv = *(const bf16x4*)zsa(z0, c4);
                float p0 = pp[0][knbr], p1 = pp[1][knbr];
                #pragma unroll
                for (int i = 0; i < 4; ++i) {
                    float zf = (float)zv[i];
                    a0[i] += p0 * zf;
                    a1[i] += p1 * zf;
                }
            }
            bf16x4 o0, o1;
            #pragma unroll
            for (int i = 0; i < 4; ++i) { o0[i] = (bf16)a0[i]; o1[i] = (bf16)a1[i]; }
            *(bf16x4*)(ZB + (size_t)(iA + nsel) * 1152 + c4)       = o0;   // head 0
            *(bf16x4*)(ZB + (size_t)(iA + nsel) * 1152 + 576 + c4) = o1;   // head 1
        }
    }
}

// ---------------- LayerNorm + build X: wave-per-row, 4 rows/block, no barriers ----------------
__global__ __launch_bounds__(256)
void ln_x_kernel(const float* __restrict__ fcr, const float* __restrict__ g,
                 const float* __restrict__ b, const bf16* __restrict__ nh16,
                 bf16* __restrict__ X) {
    const int lane = threadIdx.x & 63;
    const size_t i = (size_t)blockIdx.x * 4 + (threadIdx.x >> 6);
    if (i >= NN) return;

    float v[9];
    float s = 0.f, ss = 0.f;
    #pragma unroll
    for (int it = 0; it < 9; ++it) {
        int c = lane + it * 64;
        v[it] = (c < 516) ? fcr[i * 516 + c] : 0.f;
        s += v[it]; ss += v[it] * v[it];
    }
    #pragma unroll
    for (int o = 32; o >= 1; o >>= 1) {
        s  += __shfl_xor(s, o);
        ss += __shfl_xor(ss, o);
    }
    float mean = s / 516.f;
    float rstd = rsqrtf(ss / 516.f - mean * mean + 1e-5f);

    #pragma unroll
    for (int it = 0; it < 9; ++it) {
        int c = lane + it * 64;
        if (c < 516)
            X[i * 704 + c] = (bf16)((v[it] - mean) * rstd * g[c] + b[c]);
    }
    #pragma unroll
    for (int it = 0; it < 3; ++it) {
        int c = 516 + lane + it * 64;
        if (c < 704)
            X[i * 704 + c] = (c < 688) ? nh16[i * 192 + (c - 516)] : (bf16)0.f;
    }
}

// ---------------- launch ----------------
extern "C" void kernel_launch(void* const* d_in, const int* in_sizes, int n_in,
                              void* d_out, int out_size, void* d_ws, size_t ws_size,
                              hipStream_t stream) {
    const float* node_h     = (const float*)d_in[0];
    const float* edge_t     = (const float*)d_in[1];
    const float* edge_feat  = (const float*)d_in[2];
    const int*   nbr_idx    = (const int*)d_in[3];
    const float* t_now      = (const float*)d_in[4];
    const float* w_q        = (const float*)d_in[6];
    const float* w_k        = (const float*)d_in[7];
    const float* w_v        = (const float*)d_in[8];
    const float* basis_freq = (const float*)d_in[9];
    const float* phase      = (const float*)d_in[10];
    const float* ln_g       = (const float*)d_in[11];
    const float* ln_b       = (const float*)d_in[12];
    const float* fc_w       = (const float*)d_in[13];
    const float* fc_b       = (const float*)d_in[14];
    const float* m1_w       = (const float*)d_in[15];
    const float* m1_b       = (const float*)d_in[16];
    const float* m2_w       = (const float*)d_in[17];
    const float* m2_b       = (const float*)d_in[18];

    char* ws = (char*)d_ws;
    bf16*  FCWT = (bf16*)(ws + FCWT_OFF);
    bf16*  M1WT = (bf16*)(ws + M1WT_OFF);
    bf16*  M2WT = (bf16*)(ws + M2WT_OFF);
    bf16*  WKH  = (bf16*)(ws + WKH_OFF);
    bf16*  WQHT = (bf16*)(ws + WQHT_OFF);
    bf16*  WVH  = (bf16*)(ws + WVH_OFF);
    bf16*  WQKT = (bf16*)(ws + WQKT_OFF);
    bf16*  WVFT = (bf16*)(ws + WVFT_OFF);
    float* QB   = (float*)(ws + QB_OFF);
    float* QKB  = (float*)(ws + QKB_OFF);
    float* CPH  = (float*)(ws + CPH_OFF);
    bf16*  NH16 = (bf16*)(ws + NH16_OFF);
    bf16*  QK   = (bf16*)(ws + QK_OFF);
    bf16*  ZB   = (bf16*)(ws + ZB_OFF);
    float* FCR  = (float*)(ws + FCR_OFF);
    bf16*  Xb   = (bf16*)(ws + X_OFF);
    bf16*  Rb   = (bf16*)(ws + R_OFF);

    hipMemsetAsync(ws, 0, NH16_OFF, stream);

    // all prep in one launch: y0-2 transpose-packs, y3 misc, y4 qbias
    prep_all_kernel<<<dim3(1024, 5), 256, 0, stream>>>(
        fc_w, m1_w, m2_w, w_k, w_q, w_v, node_h, phase,
        FCWT, M1WT, M2WT, WKH, WQHT, WVH, NH16, CPH, QB);
    qkb_kernel<<<1152, 256, 0, stream>>>(w_k, QB, QKB);

    // WQK^T (z=0,1) and WVF^T (z=2,3) in one launch
    gemm_multi_kernel<<<dim3(4, 5, 4), 256, 0, stream>>>(WKH, WQHT, FCWT, WVH, WQKT, WVFT);

    // qk = NH16 @ WQK^T + qkb   -> QK [NPAD][1152]   (BM=64, 2 blocks/CU)
    gemm_kernel<192, 0, 1><<<dim3(7, 158), 256, 0, stream>>>(
        NH16, 192, WQKT, nullptr, QK, 1152, QKB, nullptr, nullptr, NN, 1152);

    // attention -> ZB [NPAD][1152]
    attn_lite_kernel<<<NN / 2, 256, 0, stream>>>(
        QK, NH16, edge_feat, edge_t, nbr_idx, basis_freq, phase, t_now, ZB);

    // fcr = ZB @ WVF^T + fc_b + self_z   (BM=64)
    gemm_kernel<1152, 2, 1><<<dim3(3, 158), 256, 0, stream>>>(
        ZB, 1152, WVFT, FCR, nullptr, 516, fc_b, node_h, CPH, NN, 516);

    // LayerNorm + X build: wave-per-row
    ln_x_kernel<<<(NN + 3) / 4, 256, 0, stream>>>(FCR, ln_g, ln_b, NH16, Xb);

    // m1 + relu  (BM=64; cols 172..175 zeroed so m2 A-loads are clean)
    gemm_kernel<704, 3, 1><<<dim3(1, 158), 256, 0, stream>>>(
        Xb, 704, M1WT, nullptr, Rb, 192, m1_b, nullptr, nullptr, NN, 172);

    // m2 -> out  (BM=64; K-pad rows of M2WT are zero so poison A cols are inert)
    gemm_kernel<192, 4, 1><<<dim3(1, 158), 256, 0, stream>>>(
        Rb, 192, M2WT, (float*)d_out, nullptr, 172, m2_b, nullptr, nullptr, NN, 172);
}